// Round 13
// baseline (351.386 us; speedup 1.0000x reference)
//
#include <hip/hip_runtime.h>
#include <hip/hip_bf16.h>

#define B_ 4
#define S_ 2048
#define H_ 768
#define NH_ 12
#define HD_ 64
#define MLP_ 3072
#define M_ (B_*S_)

typedef float f32x4 __attribute__((ext_vector_type(4)));
typedef short bf16x8 __attribute__((ext_vector_type(8)));

__device__ __forceinline__ short f2bf(float f) {
  union { float f; unsigned u; } x; x.f = f;
  unsigned r = (x.u + 0x7fffu + ((x.u >> 16) & 1u)) >> 16;
  return (short)(unsigned short)r;
}

__device__ __forceinline__ float exp2g(float x) {   // raw v_exp_f32 (2^x)
  float r; asm("v_exp_f32 %0, %1" : "=v"(r) : "v"(x)); return r;
}
__device__ __forceinline__ float rcpg(float x) {    // raw v_rcp_f32
  float r; asm("v_rcp_f32 %0, %1" : "=v"(r) : "v"(x)); return r;
}
__device__ __forceinline__ float max3g(float a, float b, float c) {
  float r; asm("v_max3_f32 %0, %1, %2, %3" : "=v"(r) : "v"(a), "v"(b), "v"(c)); return r;
}
__device__ __forceinline__ unsigned cvtpk(float a, float b) { // [bf16(a)|bf16(b)<<16]
  unsigned r; asm("v_cvt_pk_bf16_f32 %0, %1, %2" : "=v"(r) : "v"(a), "v"(b)); return r;
}

typedef __attribute__((address_space(1))) const void gvoid;
typedef __attribute__((address_space(3))) void lvoid;
__device__ __forceinline__ void async16(const void* g, void* l) {
  __builtin_amdgcn_global_load_lds((gvoid*)g, (lvoid*)l, 16, 0, 0);
}

// bijective XCD chunk swizzle (m204): hw linear id -> logical id such that each
// XCD owns a CONTIGUOUS logical span (L2 locality for panel reuse).
__device__ __forceinline__ int xcd_swz(int h, int nwg) {
  const int q = nwg >> 3, r = nwg & 7;
  const int xc = h & 7, i = h >> 3;
  return (xc < r ? xc * (q + 1) : r * (q + 1) + (xc - r) * q) + i;
}

// ---------------- weight transpose+cast: out[n*K+k] = bf16(in[k*N+n]) ----------
__global__ __launch_bounds__(256)
void tcast(const float* __restrict__ in, short* __restrict__ out, int K, int N) {
  __shared__ float tile[32][33];
  const int n0 = blockIdx.x * 32, k0 = blockIdx.y * 32;
  const int tx = threadIdx.x, ty = threadIdx.y;
#pragma unroll
  for (int i = 0; i < 4; ++i)
    tile[ty * 4 + i][tx] = in[(size_t)(k0 + ty * 4 + i) * N + n0 + tx];
  __syncthreads();
#pragma unroll
  for (int i = 0; i < 4; ++i)
    out[(size_t)(n0 + ty * 4 + i) * K + k0 + tx] = f2bf(tile[tx][ty * 4 + i]);
}

// four 768x768 transposes in one launch (z selects)
__global__ __launch_bounds__(256)
void tcast4(const float* __restrict__ i0, const float* __restrict__ i1,
            const float* __restrict__ i2, const float* __restrict__ i3,
            short* __restrict__ o0, short* __restrict__ o1,
            short* __restrict__ o2, short* __restrict__ o3) {
  __shared__ float tile[32][33];
  const int z = blockIdx.z;
  const float* in = (z == 0) ? i0 : (z == 1) ? i1 : (z == 2) ? i2 : i3;
  short* out = (z == 0) ? o0 : (z == 1) ? o1 : (z == 2) ? o2 : o3;
  const int n0 = blockIdx.x * 32, k0 = blockIdx.y * 32;
  const int tx = threadIdx.x, ty = threadIdx.y;
#pragma unroll
  for (int i = 0; i < 4; ++i)
    tile[ty * 4 + i][tx] = in[(size_t)(k0 + ty * 4 + i) * 768 + n0 + tx];
  __syncthreads();
#pragma unroll
  for (int i = 0; i < 4; ++i)
    out[(size_t)(n0 + ty * 4 + i) * 768 + k0 + tx] = f2bf(tile[tx][ty * 4 + i]);
}

// ---------------- layernorm (row of 768) -> bf16 ------------------------------
__device__ __forceinline__ float block_sum256(float v) {
  __shared__ float red[4];
#pragma unroll
  for (int o = 32; o > 0; o >>= 1) v += __shfl_down(v, o);
  if ((threadIdx.x & 63) == 0) red[threadIdx.x >> 6] = v;
  __syncthreads();
  v = red[0] + red[1] + red[2] + red[3];
  __syncthreads();
  return v;
}

__global__ __launch_bounds__(256)
void ln_fwd(const float* __restrict__ xin, const float* __restrict__ g,
            const float* __restrict__ bt, short* __restrict__ o) {
  const int row = blockIdx.x, t = threadIdx.x;
  const float* xr = xin + (size_t)row * H_;
  const float v0 = xr[t], v1 = xr[t + 256], v2 = xr[t + 512];
  const float mean = block_sum256(v0 + v1 + v2) * (1.0f / H_);
  const float d0 = v0 - mean, d1 = v1 - mean, d2 = v2 - mean;
  const float var = block_sum256(d0 * d0 + d1 * d1 + d2 * d2) * (1.0f / H_);
  const float rstd = rsqrtf(var + 1e-6f);
  short* orow = o + (size_t)row * H_;
  orow[t]       = f2bf(d0 * rstd * g[t] + bt[t]);
  orow[t + 256] = f2bf(d1 * rstd * g[t + 256] + bt[t + 256]);
  orow[t + 512] = f2bf(d2 * rstd * g[t + 512] + bt[t + 512]);
}

// ---------------- GEMM: C[M][N] = A[M][K](bf16) * Bw[N][K]^T(bf16) ------------
// TRIPLE-BUFFERED + COUNTED VMCNT (T4): per-wave FIFO -> s_waitcnt vmcnt(6)
// before the raw s_barrier guarantees stage(it) landed while stage(it+1/it+2)
// stay in flight (loads get TWO compute phases to land; no full drain except
// the last iter). Tile 128x64, BK=64, LDS 72 KB -> 2 blocks/CU.
// XOR staging/read swizzle; XCD chunk swizzle (bn-fastest logical).
#define QSCALE 0.18033688011112042f   /* 0.125 * log2(e) */
template<int MODE>
__global__ __launch_bounds__(256)
void gemm_bt(const short* __restrict__ A, const short* __restrict__ Bw,
             int K, int N,
             const float* __restrict__ b0, const float* __restrict__ b1,
             const float* __restrict__ b2,
             const float* __restrict__ resid,
             float* __restrict__ outf, short* __restrict__ outh,
             short* __restrict__ oq, short* __restrict__ ok2, short* __restrict__ ov) {
  __shared__ short As[3][128 * 64];
  __shared__ short Bs[3][64 * 64];
  const int tid = threadIdx.x;
  const int wv = tid >> 6, lane = tid & 63;
  const int lo = lane & 15, hi = lane >> 4;
  const int wr = wv >> 1, wc = wv & 1;

  const int GX = gridDim.x;
  const int logical = xcd_swz(blockIdx.y * GX + blockIdx.x, GX * gridDim.y);
  const int bn = logical % GX, bm = logical / GX;

  const short* Ab = A + (size_t)bm * 128 * K;
  const short* Bb = Bw + (size_t)bn * 64 * K;
  const int srow = lane >> 3;                 // row within 8-row staging call
  const int scol = ((lane & 7) ^ srow) * 8;   // pre-swizzled source col chunk

  auto stage = [&](int buf, int kt) {
#pragma unroll
    for (int c = 0; c < 4; ++c) {             // A: 32 rows/wave
      const int rb = wv * 32 + c * 8;
      async16(Ab + (size_t)(rb + srow) * K + kt + scol, &As[buf][rb * 64]);
    }
#pragma unroll
    for (int c = 0; c < 2; ++c) {             // B: 16 rows/wave
      const int rb = wv * 16 + c * 8;
      async16(Bb + (size_t)(rb + srow) * K + kt + scol, &Bs[buf][rb * 64]);
    }
  };

  f32x4 acc[4][2] = {};
  const int nIt = K >> 6;
  stage(0, 0);
  stage(1, 64);
  for (int it = 0; it < nIt; ++it) {
    // per-wave FIFO: <=6 outstanding <=> everything older than stage(it+1) done
    if (it < nIt - 1) asm volatile("s_waitcnt vmcnt(6)" ::: "memory");
    else              asm volatile("s_waitcnt vmcnt(0)" ::: "memory");
    __builtin_amdgcn_s_barrier();
    if (it + 2 < nIt) stage((it + 2) % 3, (it + 2) << 6);  // 2 phases to land
    const short* as = As[it % 3];
    const short* bs = Bs[it % 3];
#pragma unroll
    for (int ks = 0; ks < 2; ++ks) {
      const int rc = (((ks * 4 + hi) ^ (lo & 7)) * 8);  // swizzled read chunk
      bf16x8 af[4], bfr[2];
#pragma unroll
      for (int m = 0; m < 4; ++m)
        af[m] = *(const bf16x8*)&as[(wr * 64 + m * 16 + lo) * 64 + rc];
#pragma unroll
      for (int n = 0; n < 2; ++n)
        bfr[n] = *(const bf16x8*)&bs[(wc * 32 + n * 16 + lo) * 64 + rc];
#pragma unroll
      for (int m = 0; m < 4; ++m)
#pragma unroll
        for (int n = 0; n < 2; ++n)
          acc[m][n] = __builtin_amdgcn_mfma_f32_16x16x32_bf16(af[m], bfr[n], acc[m][n], 0, 0, 0);
    }
  }
  const int colBase = bn * 64 + wc * 32;
  const int rowBase = bm * 128 + wr * 64;
#pragma unroll
  for (int m = 0; m < 4; ++m) {
#pragma unroll
    for (int n = 0; n < 2; ++n) {
#pragma unroll
      for (int r = 0; r < 4; ++r) {
        const int row = rowBase + m * 16 + hi * 4 + r;
        const int col = colBase + n * 16 + lo;
        float val = acc[m][n][r];
        if (MODE == 0) {
          const int which = col / H_;
          const int nn = col - which * H_;
          val += (which == 0 ? b0 : which == 1 ? b1 : b2)[nn];
          if (which == 0) val *= QSCALE;   // fold softmax scale + log2e into Q
          const int h = nn >> 6, d = nn & 63;
          const int bI = row >> 11, s = row & (S_ - 1);
          const short bv16 = f2bf(val);
          if (which == 2) {   // V^T layout, key-permuted within 64-blocks
            const int sl = s & 63;
            const int pc = ((sl >> 4) & 1) * 32 + ((sl >> 2) & 3) * 8
                         + ((sl >> 5) & 1) * 4 + (sl & 3);
            ov[(((size_t)bI * NH_ + h) * HD_ + d) * S_ + (s & ~63) + pc] = bv16;
          } else {
            short* dst = (which == 0 ? oq : ok2);
            dst[(((size_t)bI * NH_ + h) * S_ + s) * HD_ + d] = bv16;
          }
        } else if (MODE == 1) {
          val += b0[col] + resid[(size_t)row * N + col];
          outf[(size_t)row * N + col] = val;
        } else {
          val += b0[col];
          // tanh-gelu: x * sigmoid(2u), u = 0.79788456(x + 0.044715 x^3)
          const float u = val * (0.7978845608f + 0.0356774081f * val * val);
          const float e = exp2g(-2.885390082f * u);   // exp(-2u)
          val = val * rcpg(1.0f + e);
          outh[(size_t)row * N + col] = f2bf(val);
        }
      }
    }
  }
}

// ---------------- flash attention (swapped QK^T, P in registers, 2 q-groups) ---
// grid (S/128, B*NH) with XCD chunk swizzle. 4 waves; each wave handles TWO
// q-groups (rows q0..q0+15, q0+64..q0+79). Single barrier/tile, double-buffered
// K/V LDS. Stage-write + t+2 prefetch HOISTED above QK^T (issue earlier; the
// end-of-body barrier already separates this write from last tile's readers).
// QK^T as mfma(K,Q) with C-init = -mrow; per-lane max3 tree gates rare
// wave-uniform fixup; l via ones-column MFMA; P in registers (cvtpk pack IS
// the PV A-operand; V^T key-permuted per 64-block).
__global__ __launch_bounds__(256)
void attn_fwd(const short* __restrict__ qbuf, const short* __restrict__ kbuf,
              const short* __restrict__ vbuf, short* __restrict__ ctx) {
  __shared__ short Ks[2][8 * 512];
  __shared__ short Vt[2][8 * 512];
  const int tid = threadIdx.x;
  const int wv = tid >> 6, lane = tid & 63;
  const int lo = lane & 15, hi = lane >> 4;
  const int logical = xcd_swz(blockIdx.y * 16 + blockIdx.x, 16 * 48);
  const int qt = logical & 15, bh = logical >> 4;
  const int bI = bh / NH_, h = bh - bI * NH_;
  const size_t baseBH = (size_t)bh * S_ * HD_;
  const int q0 = qt * 128 + wv * 16;       // group A; group B = q0 + 64

  bf16x8 qfA[2], qfB[2];  // B-operand: Q[qrow][d = k2*32 + hi*8 ..+7]
#pragma unroll
  for (int k2 = 0; k2 < 2; ++k2) {
    qfA[k2] = *(const bf16x8*)&qbuf[baseBH + (size_t)(q0 + lo) * HD_ + k2 * 32 + hi * 8];
    qfB[k2] = *(const bf16x8*)&qbuf[baseBH + (size_t)(q0 + 64 + lo) * HD_ + k2 * 32 + hi * 8];
  }

  f32x4 accA[4] = {}, accB[4] = {};
  f32x4 accSA = {}, accSB = {};         // row-sums via ones-column MFMA
  float nmA = 0.0f, nmB = 0.0f;         // -mrow per group

  // ones B-fragment: column 0 all ones -> C[:,0] = row-sum of A
  const short oo = (lo == 0) ? (short)0x3F80 : (short)0;
  const bf16x8 onesf = {oo, oo, oo, oo, oo, oo, oo, oo};

  // staging: wave wv owns frags {2wv,2wv+1} of K and V (contiguous 16B/lane).
  const short* ksrc = kbuf + baseBH + (size_t)(wv * 16 + lo) * HD_ + hi * 8;
  const short* vsrc = vbuf + baseBH + (size_t)(wv * 16 + lo) * S_ + hi * 8;
  const int dst0 = wv * 1024 + lane * 8;

  bf16x8 kreg0, kreg1, vreg0, vreg1;
  // tile 0 -> regs -> buf0
  kreg0 = *(const bf16x8*)(ksrc);
  kreg1 = *(const bf16x8*)(ksrc + 32);
  vreg0 = *(const bf16x8*)(vsrc);
  vreg1 = *(const bf16x8*)(vsrc + 32);
  *(bf16x8*)&Ks[0][dst0] = kreg0;
  *(bf16x8*)&Ks[0][dst0 + 512] = kreg1;
  *(bf16x8*)&Vt[0][dst0] = vreg0;
  *(bf16x8*)&Vt[0][dst0 + 512] = vreg1;
  // tile 1 -> regs
  kreg0 = *(const bf16x8*)(ksrc + (size_t)64 * HD_);
  kreg1 = *(const bf16x8*)(ksrc + (size_t)64 * HD_ + 32);
  vreg0 = *(const bf16x8*)(vsrc + 64);
  vreg1 = *(const bf16x8*)(vsrc + 64 + 32);
  __syncthreads();

  for (int t = 0; t < S_ / 64; ++t) {
    const int cur = t & 1, nxt = cur ^ 1;
    // ---- stage tile t+1 regs -> spare buffer (safe: barrier(t-1) passed) ----
    *(bf16x8*)&Ks[nxt][dst0] = kreg0;
    *(bf16x8*)&Ks[nxt][dst0 + 512] = kreg1;
    *(bf16x8*)&Vt[nxt][dst0] = vreg0;
    *(bf16x8*)&Vt[nxt][dst0 + 512] = vreg1;
    // ---- prefetch tile t+2 -> regs (issued ASAP; lands during next body) ----
    {
      const int tn = (t + 2 < S_ / 64) ? t + 2 : S_ / 64 - 1;
      const short* kp = ksrc + (size_t)tn * 64 * HD_;
      kreg0 = *(const bf16x8*)(kp);
      kreg1 = *(const bf16x8*)(kp + 32);
      const short* vp = vsrc + tn * 64;
      vreg0 = *(const bf16x8*)(vp);
      vreg1 = *(const bf16x8*)(vp + 32);
    }
    const short* ks = Ks[cur];
    const short* vt = Vt[cur];
    // ---- QK^T both groups (each kf read feeds 2 MFMAs); C-init = -mrow ----
    const f32x4 ciA = {nmA, nmA, nmA, nmA};
    const f32x4 ciB = {nmB, nmB, nmB, nmB};
    f32x4 scA[4], scB[4];
    __builtin_amdgcn_s_setprio(1);
#pragma unroll
    for (int nk = 0; nk < 4; ++nk) {
      f32x4 zA = ciA, zB = ciB;
#pragma unroll
      for (int k2 = 0; k2 < 2; ++k2) {
        bf16x8 kf = *(const bf16x8*)&ks[(nk * 2 + k2) * 512 + lane * 8];
        zA = __builtin_amdgcn_mfma_f32_16x16x32_bf16(kf, qfA[k2], zA, 0, 0, 0);
        zB = __builtin_amdgcn_mfma_f32_16x16x32_bf16(kf, qfB[k2], zB, 0, 0, 0);
      }
      scA[nk] = zA; scB[nk] = zB;
    }
    __builtin_amdgcn_s_setprio(0);
    // ---- per-lane max trees (off the exp path) ----
    float mxA = max3g(scA[0][0], scA[0][1], scA[0][2]);
    mxA = max3g(mxA, scA[0][3], scA[1][0]);
    mxA = max3g(mxA, scA[1][1], scA[1][2]);
    mxA = max3g(mxA, scA[1][3], scA[2][0]);
    mxA = max3g(mxA, scA[2][1], scA[2][2]);
    mxA = max3g(mxA, scA[2][3], scA[3][0]);
    mxA = max3g(mxA, scA[3][1], scA[3][2]);
    mxA = fmaxf(mxA, scA[3][3]);
    float mxB = max3g(scB[0][0], scB[0][1], scB[0][2]);
    mxB = max3g(mxB, scB[0][3], scB[1][0]);
    mxB = max3g(mxB, scB[1][1], scB[1][2]);
    mxB = max3g(mxB, scB[1][3], scB[2][0]);
    mxB = max3g(mxB, scB[2][1], scB[2][2]);
    mxB = max3g(mxB, scB[2][3], scB[3][0]);
    mxB = max3g(mxB, scB[3][1], scB[3][2]);
    mxB = fmaxf(mxB, scB[3][3]);
    // ---- speculative exp straight off the MFMA results (both groups) ----
#pragma unroll
    for (int nk = 0; nk < 4; ++nk)
#pragma unroll
      for (int r = 0; r < 4; ++r) {
        scA[nk][r] = exp2g(scA[nk][r]);
        scB[nk][r] = exp2g(scB[nk][r]);
      }
    if (!__all(fmaxf(mxA, mxB) <= 8.0f)) {   // rare fixup; alphas wave-uniform
      mxA = fmaxf(mxA, __shfl_xor(mxA, 16));
      mxA = fmaxf(mxA, __shfl_xor(mxA, 32));
      mxB = fmaxf(mxB, __shfl_xor(mxB, 16));
      mxB = fmaxf(mxB, __shfl_xor(mxB, 32));
      const float dA = fmaxf(mxA, 0.0f), dB = fmaxf(mxB, 0.0f);
      const float aA = exp2g(-dA), aB = exp2g(-dB);
      nmA -= dA; nmB -= dB;
#pragma unroll
      for (int nk = 0; nk < 4; ++nk)
#pragma unroll
        for (int r = 0; r < 4; ++r) { scA[nk][r] *= aA; scB[nk][r] *= aB; }
      accSA *= aA; accSB *= aB;
#pragma unroll
      for (int nd = 0; nd < 4; ++nd) { accA[nd] *= aA; accB[nd] *= aB; }
    }
    // ---- pack P into PV A-operands (perm pos = 32(nk&1)+8hi+4(nk>>1)+r) ----
    union PU { unsigned u[4]; bf16x8 v; } pA0, pA1, pB0, pB1;
    pA0.u[0] = cvtpk(scA[0][0], scA[0][1]); pA0.u[1] = cvtpk(scA[0][2], scA[0][3]);
    pA0.u[2] = cvtpk(scA[2][0], scA[2][1]); pA0.u[3] = cvtpk(scA[2][2], scA[2][3]);
    pA1.u[0] = cvtpk(scA[1][0], scA[1][1]); pA1.u[1] = cvtpk(scA[1][2], scA[1][3]);
    pA1.u[2] = cvtpk(scA[3][0], scA[3][1]); pA1.u[3] = cvtpk(scA[3][2], scA[3][3]);
    pB0.u[0] = cvtpk(scB[0][0], scB[0][1]); pB0.u[1] = cvtpk(scB[0][2], scB[0][3]);
    pB0.u[2] = cvtpk(scB[2][0], scB[2][1]); pB0.u[3] = cvtpk(scB[2][2], scB[2][3]);
    pB1.u[0] = cvtpk(scB[1][0], scB[1][1]); pB1.u[1] = cvtpk(scB[1][2], scB[1][3]);
    pB1.u[2] = cvtpk(scB[3][0], scB[3][1]); pB1.u[3] = cvtpk(scB[3][2], scB[3][3]);
    // ---- PV + row-sums (each vf read feeds 2 MFMAs) ----
    __builtin_amdgcn_s_setprio(1);
    accSA = __builtin_amdgcn_mfma_f32_16x16x32_bf16(pA0.v, onesf, accSA, 0, 0, 0);
    accSA = __builtin_amdgcn_mfma_f32_16x16x32_bf16(pA1.v, onesf, accSA, 0, 0, 0);
    accSB = __builtin_amdgcn_mfma_f32_16x16x32_bf16(pB0.v, onesf, accSB, 0, 0, 0);
    accSB = __builtin_amdgcn_mfma_f32_16x16x32_bf16(pB1.v, onesf, accSB, 0, 0, 0);
#pragma unroll
    for (int nd = 0; nd < 4; ++nd) {
      bf16x8 vf0 = *(const bf16x8*)&vt[(nd * 2 + 0) * 512 + lane * 8];
      accA[nd] = __builtin_amdgcn_mfma_f32_16x16x32_bf16(pA0.v, vf0, accA[nd], 0, 0, 0);
      accB[nd] = __builtin_amdgcn_mfma_f32_16x16x32_bf16(pB0.v, vf0, accB[nd], 0, 0, 0);
      bf16x8 vf1 = *(const bf16x8*)&vt[(nd * 2 + 1) * 512 + lane * 8];
      accA[nd] = __builtin_amdgcn_mfma_f32_16x16x32_bf16(pA1.v, vf1, accA[nd], 0, 0, 0);
      accB[nd] = __builtin_amdgcn_mfma_f32_16x16x32_bf16(pB1.v, vf1, accB[nd], 0, 0, 0);
    }
    __builtin_amdgcn_s_setprio(0);
    __syncthreads();                      // single barrier per tile
  }
  // ---- epilogue: O[q][d=16nd+lo]; l(q=4hi+r) = accS[r] @ lane hi*16 ----
#pragma unroll
  for (int r = 0; r < 4; ++r) {
    const float invA = rcpg(__shfl(accSA[r], hi << 4));
    const float invB = rcpg(__shfl(accSB[r], hi << 4));
    const int srA = q0 + hi * 4 + r;
    const size_t roA = ((size_t)bI * S_ + srA) * H_ + h * HD_;
    const size_t roB = ((size_t)bI * S_ + srA + 64) * H_ + h * HD_;
#pragma unroll
    for (int nd = 0; nd < 4; ++nd) {
      ctx[roA + nd * 16 + lo] = f2bf(accA[nd][r] * invA);
      ctx[roB + nd * 16 + lo] = f2bf(accB[nd][r] * invB);
    }
  }
}

// ---------------- launch -------------------------------------------------------
extern "C" void kernel_launch(void* const* d_in, const int* in_sizes, int n_in,
                              void* d_out, int out_size, void* d_ws, size_t ws_size,
                              hipStream_t stream) {
  const float* x    = (const float*)d_in[0];
  const float* ln1w = (const float*)d_in[1];
  const float* ln1b = (const float*)d_in[2];
  const float* wq   = (const float*)d_in[3];
  const float* bq   = (const float*)d_in[4];
  const float* wk   = (const float*)d_in[5];
  const float* bk   = (const float*)d_in[6];
  const float* wvp  = (const float*)d_in[7];
  const float* bv   = (const float*)d_in[8];
  const float* wo   = (const float*)d_in[9];
  const float* bo   = (const float*)d_in[10];
  const float* ln2w = (const float*)d_in[11];
  const float* ln2b = (const float*)d_in[12];
  const float* w1   = (const float*)d_in[13];
  const float* b1   = (const float*)d_in[14];
  const float* w2   = (const float*)d_in[15];
  const float* b2   = (const float*)d_in[16];
  float* out = (float*)d_out;

  short* ws = (short*)d_ws;
  short* wqkvT = ws;                              // [2304][768]
  short* woT   = wqkvT + (size_t)2304 * 768;      // [768][768]
  short* w1T   = woT + (size_t)768 * 768;         // [3072][768]
  short* w2T   = w1T + (size_t)3072 * 768;        // [768][3072]
  short* xn    = w2T + (size_t)768 * 3072;        // [8192][768] (reused as xn2)
  short* qb    = xn + (size_t)M_ * H_;            // [48][2048][64]
  short* kb    = qb + (size_t)M_ * H_;
  short* vb    = kb + (size_t)M_ * H_;            // V^T: [48][64][2048]
  short* ctx   = vb + (size_t)M_ * H_;            // [8192][768]
  short* yb    = qb;                              // reuse q..ctx: [8192][3072]
  float* x1    = (float*)(ctx + (size_t)M_ * H_); // [8192][768] fp32

  dim3 tb(32, 8);
  tcast4<<<dim3(24, 24, 4), tb, 0, stream>>>(wq, wk, wvp, wo,
      wqkvT, wqkvT + (size_t)768 * 768, wqkvT + (size_t)2 * 768 * 768, woT);
  tcast<<<dim3(96, 24), tb, 0, stream>>>(w1, w1T, 768, 3072);
  tcast<<<dim3(24, 96), tb, 0, stream>>>(w2, w2T, 3072, 768);

  ln_fwd<<<M_, 256, 0, stream>>>(x, ln1w, ln1b, xn);

  gemm_bt<0><<<dim3(36, 64), 256, 0, stream>>>(xn, wqkvT, 768, 2304,
      bq, bk, bv, nullptr, nullptr, nullptr, qb, kb, vb);

  attn_fwd<<<dim3(16, 48), 256, 0, stream>>>(qb, kb, vb, ctx);

  gemm_bt<1><<<dim3(12, 64), 256, 0, stream>>>(ctx, woT, 768, 768,
      bo, nullptr, nullptr, x, x1, nullptr, nullptr, nullptr, nullptr);

  ln_fwd<<<M_, 256, 0, stream>>>(x1, ln2w, ln2b, xn);

  gemm_bt<2><<<dim3(48, 64), 256, 0, stream>>>(xn, w1T, 768, 3072,
      b1, nullptr, nullptr, nullptr, nullptr, yb, nullptr, nullptr, nullptr);

  gemm_bt<1><<<dim3(12, 64), 256, 0, stream>>>(yb, w2T, 3072, 768,
      b2, nullptr, nullptr, x1, out, nullptr, nullptr, nullptr, nullptr);
}

// Round 14
// 336.982 us; speedup vs baseline: 1.0427x; 1.0427x over previous
//
#include <hip/hip_runtime.h>
#include <hip/hip_bf16.h>

#define B_ 4
#define S_ 2048
#define H_ 768
#define NH_ 12
#define HD_ 64
#define MLP_ 3072
#define M_ (B_*S_)

typedef float f32x4 __attribute__((ext_vector_type(4)));
typedef short bf16x8 __attribute__((ext_vector_type(8)));

__device__ __forceinline__ short f2bf(float f) {
  union { float f; unsigned u; } x; x.f = f;
  unsigned r = (x.u + 0x7fffu + ((x.u >> 16) & 1u)) >> 16;
  return (short)(unsigned short)r;
}

__device__ __forceinline__ float exp2g(float x) {   // raw v_exp_f32 (2^x)
  float r; asm("v_exp_f32 %0, %1" : "=v"(r) : "v"(x)); return r;
}
__device__ __forceinline__ float rcpg(float x) {    // raw v_rcp_f32
  float r; asm("v_rcp_f32 %0, %1" : "=v"(r) : "v"(x)); return r;
}
__device__ __forceinline__ float max3g(float a, float b, float c) {
  float r; asm("v_max3_f32 %0, %1, %2, %3" : "=v"(r) : "v"(a), "v"(b), "v"(c)); return r;
}
__device__ __forceinline__ unsigned cvtpk(float a, float b) { // [bf16(a)|bf16(b)<<16]
  unsigned r; asm("v_cvt_pk_bf16_f32 %0, %1, %2" : "=v"(r) : "v"(a), "v"(b)); return r;
}

typedef __attribute__((address_space(1))) const void gvoid;
typedef __attribute__((address_space(3))) void lvoid;
__device__ __forceinline__ void async16(const void* g, void* l) {
  __builtin_amdgcn_global_load_lds((gvoid*)g, (lvoid*)l, 16, 0, 0);
}

// bijective XCD chunk swizzle (m204): hw linear id -> logical id such that each
// XCD owns a CONTIGUOUS logical span (L2 locality for panel reuse).
__device__ __forceinline__ int xcd_swz(int h, int nwg) {
  const int q = nwg >> 3, r = nwg & 7;
  const int xc = h & 7, i = h >> 3;
  return (xc < r ? xc * (q + 1) : r * (q + 1) + (xc - r) * q) + i;
}

// ---------------- weight transpose+cast: out[n*K+k] = bf16(in[k*N+n]) ----------
__global__ __launch_bounds__(256)
void tcast(const float* __restrict__ in, short* __restrict__ out, int K, int N) {
  __shared__ float tile[32][33];
  const int n0 = blockIdx.x * 32, k0 = blockIdx.y * 32;
  const int tx = threadIdx.x, ty = threadIdx.y;
#pragma unroll
  for (int i = 0; i < 4; ++i)
    tile[ty * 4 + i][tx] = in[(size_t)(k0 + ty * 4 + i) * N + n0 + tx];
  __syncthreads();
#pragma unroll
  for (int i = 0; i < 4; ++i)
    out[(size_t)(n0 + ty * 4 + i) * K + k0 + tx] = f2bf(tile[tx][ty * 4 + i]);
}

// four 768x768 transposes in one launch (z selects)
__global__ __launch_bounds__(256)
void tcast4(const float* __restrict__ i0, const float* __restrict__ i1,
            const float* __restrict__ i2, const float* __restrict__ i3,
            short* __restrict__ o0, short* __restrict__ o1,
            short* __restrict__ o2, short* __restrict__ o3) {
  __shared__ float tile[32][33];
  const int z = blockIdx.z;
  const float* in = (z == 0) ? i0 : (z == 1) ? i1 : (z == 2) ? i2 : i3;
  short* out = (z == 0) ? o0 : (z == 1) ? o1 : (z == 2) ? o2 : o3;
  const int n0 = blockIdx.x * 32, k0 = blockIdx.y * 32;
  const int tx = threadIdx.x, ty = threadIdx.y;
#pragma unroll
  for (int i = 0; i < 4; ++i)
    tile[ty * 4 + i][tx] = in[(size_t)(k0 + ty * 4 + i) * 768 + n0 + tx];
  __syncthreads();
#pragma unroll
  for (int i = 0; i < 4; ++i)
    out[(size_t)(n0 + ty * 4 + i) * 768 + k0 + tx] = f2bf(tile[tx][ty * 4 + i]);
}

// ---------------- layernorm (row of 768) -> bf16 ------------------------------
__device__ __forceinline__ float block_sum256(float v) {
  __shared__ float red[4];
#pragma unroll
  for (int o = 32; o > 0; o >>= 1) v += __shfl_down(v, o);
  if ((threadIdx.x & 63) == 0) red[threadIdx.x >> 6] = v;
  __syncthreads();
  v = red[0] + red[1] + red[2] + red[3];
  __syncthreads();
  return v;
}

__global__ __launch_bounds__(256)
void ln_fwd(const float* __restrict__ xin, const float* __restrict__ g,
            const float* __restrict__ bt, short* __restrict__ o) {
  const int row = blockIdx.x, t = threadIdx.x;
  const float* xr = xin + (size_t)row * H_;
  const float v0 = xr[t], v1 = xr[t + 256], v2 = xr[t + 512];
  const float mean = block_sum256(v0 + v1 + v2) * (1.0f / H_);
  const float d0 = v0 - mean, d1 = v1 - mean, d2 = v2 - mean;
  const float var = block_sum256(d0 * d0 + d1 * d1 + d2 * d2) * (1.0f / H_);
  const float rstd = rsqrtf(var + 1e-6f);
  short* orow = o + (size_t)row * H_;
  orow[t]       = f2bf(d0 * rstd * g[t] + bt[t]);
  orow[t + 256] = f2bf(d1 * rstd * g[t + 256] + bt[t + 256]);
  orow[t + 512] = f2bf(d2 * rstd * g[t + 512] + bt[t + 512]);
}

// ---------------- GEMM: C[M][N] = A[M][K](bf16) * Bw[N][K]^T(bf16) ------------
// BK=32 TRIPLE-BUFFER + COUNTED VMCNT (T4) at HIGH OCCUPANCY: LDS 36 KB ->
// 4 blocks/CU (16 waves). 3 staging calls/wave/iter; s_waitcnt vmcnt(3) before
// the raw s_barrier keeps the newest stage in flight -> every stage gets TWO
// compute phases to land (r13's 72KB variant had the pipeline but only
// 2 blocks/CU; this keeps both). Swizzle (rule 21, both-sides): stored chunk
// pc holds logical chunk pc ^ ((row&15)>>1 & 3); reads use hi ^ ((lo>>1)&3)
// -> 2-way max aliasing on the 8-cycle b128 floor (conflict-free).
#define QSCALE 0.18033688011112042f   /* 0.125 * log2(e) */
template<int MODE>
__global__ __launch_bounds__(256)
void gemm_bt(const short* __restrict__ A, const short* __restrict__ Bw,
             int K, int N,
             const float* __restrict__ b0, const float* __restrict__ b1,
             const float* __restrict__ b2,
             const float* __restrict__ resid,
             float* __restrict__ outf, short* __restrict__ outh,
             short* __restrict__ oq, short* __restrict__ ok2, short* __restrict__ ov) {
  __shared__ short As[3][128 * 32];
  __shared__ short Bs[3][64 * 32];
  const int tid = threadIdx.x;
  const int wv = tid >> 6, lane = tid & 63;
  const int lo = lane & 15, hi = lane >> 4;
  const int wr = wv >> 1, wc = wv & 1;

  const int GX = gridDim.x;
  const int logical = xcd_swz(blockIdx.y * GX + blockIdx.x, GX * gridDim.y);
  const int bn = logical % GX, bm = logical / GX;

  const short* Ab = A + (size_t)bm * 128 * K;
  const short* Bb = Bw + (size_t)bn * 64 * K;
  const int srow = lane >> 2;                               // row within 16-row call
  const int scol = (((lane & 3) ^ ((lane >> 3) & 3)) * 8);  // pre-swizzled src chunk

  auto stage = [&](int buf, int kt) {
#pragma unroll
    for (int c = 0; c < 2; ++c) {             // A: 32 rows/wave, 2 calls
      const int rb = wv * 32 + c * 16;
      async16(Ab + (size_t)(rb + srow) * K + kt + scol, &As[buf][rb * 32]);
    }
    {                                          // B: 16 rows/wave, 1 call
      const int rb = wv * 16;
      async16(Bb + (size_t)(rb + srow) * K + kt + scol, &Bs[buf][rb * 32]);
    }
  };

  f32x4 acc[4][2] = {};
  const int nIt = K >> 5;
  stage(0, 0);
  stage(1, 32);
  const int rc = (hi ^ ((lo >> 1) & 3)) * 8;  // swizzled read chunk (per-lane)
  for (int it = 0; it < nIt; ++it) {
    // per-wave FIFO: <=3 outstanding <=> stage(it) landed, stage(it+1) in flight
    if (it < nIt - 1) asm volatile("s_waitcnt vmcnt(3)" ::: "memory");
    else              asm volatile("s_waitcnt vmcnt(0)" ::: "memory");
    __builtin_amdgcn_s_barrier();
    if (it + 2 < nIt) stage((it + 2) % 3, (it + 2) << 5);  // 2 phases to land
    const short* as = As[it % 3];
    const short* bs = Bs[it % 3];
    bf16x8 af[4], bfr[2];
#pragma unroll
    for (int m = 0; m < 4; ++m)
      af[m] = *(const bf16x8*)&as[(wr * 64 + m * 16 + lo) * 32 + rc];
#pragma unroll
    for (int n = 0; n < 2; ++n)
      bfr[n] = *(const bf16x8*)&bs[(wc * 32 + n * 16 + lo) * 32 + rc];
#pragma unroll
    for (int m = 0; m < 4; ++m)
#pragma unroll
      for (int n = 0; n < 2; ++n)
        acc[m][n] = __builtin_amdgcn_mfma_f32_16x16x32_bf16(af[m], bfr[n], acc[m][n], 0, 0, 0);
  }
  const int colBase = bn * 64 + wc * 32;
  const int rowBase = bm * 128 + wr * 64;
#pragma unroll
  for (int m = 0; m < 4; ++m) {
#pragma unroll
    for (int n = 0; n < 2; ++n) {
#pragma unroll
      for (int r = 0; r < 4; ++r) {
        const int row = rowBase + m * 16 + hi * 4 + r;
        const int col = colBase + n * 16 + lo;
        float val = acc[m][n][r];
        if (MODE == 0) {
          const int which = col / H_;
          const int nn = col - which * H_;
          val += (which == 0 ? b0 : which == 1 ? b1 : b2)[nn];
          if (which == 0) val *= QSCALE;   // fold softmax scale + log2e into Q
          const int h = nn >> 6, d = nn & 63;
          const int bI = row >> 11, s = row & (S_ - 1);
          const short bv16 = f2bf(val);
          if (which == 2) {   // V^T layout, key-permuted within 64-blocks
            const int sl = s & 63;
            const int pc = ((sl >> 4) & 1) * 32 + ((sl >> 2) & 3) * 8
                         + ((sl >> 5) & 1) * 4 + (sl & 3);
            ov[(((size_t)bI * NH_ + h) * HD_ + d) * S_ + (s & ~63) + pc] = bv16;
          } else {
            short* dst = (which == 0 ? oq : ok2);
            dst[(((size_t)bI * NH_ + h) * S_ + s) * HD_ + d] = bv16;
          }
        } else if (MODE == 1) {
          val += b0[col] + resid[(size_t)row * N + col];
          outf[(size_t)row * N + col] = val;
        } else {
          val += b0[col];
          // tanh-gelu: x * sigmoid(2u), u = 0.79788456(x + 0.044715 x^3)
          const float u = val * (0.7978845608f + 0.0356774081f * val * val);
          const float e = exp2g(-2.885390082f * u);   // exp(-2u)
          val = val * rcpg(1.0f + e);
          outh[(size_t)row * N + col] = f2bf(val);
        }
      }
    }
  }
}

// ---------------- flash attention (swapped QK^T, P in registers, 2 q-groups) ---
// grid (S/128, B*NH) with XCD chunk swizzle. 4 waves; each wave handles TWO
// q-groups (rows q0..q0+15, q0+64..q0+79). Single barrier/tile, double-buffered
// K/V LDS. Stage-write + t+2 prefetch hoisted above QK^T. QK^T as mfma(K,Q)
// with C-init = -mrow; per-lane max3 tree gates rare wave-uniform fixup; l via
// ones-column MFMA; P in registers (cvtpk pack IS the PV A-operand; V^T
// key-permuted per 64-block).
__global__ __launch_bounds__(256)
void attn_fwd(const short* __restrict__ qbuf, const short* __restrict__ kbuf,
              const short* __restrict__ vbuf, short* __restrict__ ctx) {
  __shared__ short Ks[2][8 * 512];
  __shared__ short Vt[2][8 * 512];
  const int tid = threadIdx.x;
  const int wv = tid >> 6, lane = tid & 63;
  const int lo = lane & 15, hi = lane >> 4;
  const int logical = xcd_swz(blockIdx.y * 16 + blockIdx.x, 16 * 48);
  const int qt = logical & 15, bh = logical >> 4;
  const int bI = bh / NH_, h = bh - bI * NH_;
  const size_t baseBH = (size_t)bh * S_ * HD_;
  const int q0 = qt * 128 + wv * 16;       // group A; group B = q0 + 64

  bf16x8 qfA[2], qfB[2];  // B-operand: Q[qrow][d = k2*32 + hi*8 ..+7]
#pragma unroll
  for (int k2 = 0; k2 < 2; ++k2) {
    qfA[k2] = *(const bf16x8*)&qbuf[baseBH + (size_t)(q0 + lo) * HD_ + k2 * 32 + hi * 8];
    qfB[k2] = *(const bf16x8*)&qbuf[baseBH + (size_t)(q0 + 64 + lo) * HD_ + k2 * 32 + hi * 8];
  }

  f32x4 accA[4] = {}, accB[4] = {};
  f32x4 accSA = {}, accSB = {};         // row-sums via ones-column MFMA
  float nmA = 0.0f, nmB = 0.0f;         // -mrow per group

  // ones B-fragment: column 0 all ones -> C[:,0] = row-sum of A
  const short oo = (lo == 0) ? (short)0x3F80 : (short)0;
  const bf16x8 onesf = {oo, oo, oo, oo, oo, oo, oo, oo};

  // staging: wave wv owns frags {2wv,2wv+1} of K and V (contiguous 16B/lane).
  const short* ksrc = kbuf + baseBH + (size_t)(wv * 16 + lo) * HD_ + hi * 8;
  const short* vsrc = vbuf + baseBH + (size_t)(wv * 16 + lo) * S_ + hi * 8;
  const int dst0 = wv * 1024 + lane * 8;

  bf16x8 kreg0, kreg1, vreg0, vreg1;
  // tile 0 -> regs -> buf0
  kreg0 = *(const bf16x8*)(ksrc);
  kreg1 = *(const bf16x8*)(ksrc + 32);
  vreg0 = *(const bf16x8*)(vsrc);
  vreg1 = *(const bf16x8*)(vsrc + 32);
  *(bf16x8*)&Ks[0][dst0] = kreg0;
  *(bf16x8*)&Ks[0][dst0 + 512] = kreg1;
  *(bf16x8*)&Vt[0][dst0] = vreg0;
  *(bf16x8*)&Vt[0][dst0 + 512] = vreg1;
  // tile 1 -> regs
  kreg0 = *(const bf16x8*)(ksrc + (size_t)64 * HD_);
  kreg1 = *(const bf16x8*)(ksrc + (size_t)64 * HD_ + 32);
  vreg0 = *(const bf16x8*)(vsrc + 64);
  vreg1 = *(const bf16x8*)(vsrc + 64 + 32);
  __syncthreads();

  for (int t = 0; t < S_ / 64; ++t) {
    const int cur = t & 1, nxt = cur ^ 1;
    // ---- stage tile t+1 regs -> spare buffer (safe: barrier(t-1) passed) ----
    *(bf16x8*)&Ks[nxt][dst0] = kreg0;
    *(bf16x8*)&Ks[nxt][dst0 + 512] = kreg1;
    *(bf16x8*)&Vt[nxt][dst0] = vreg0;
    *(bf16x8*)&Vt[nxt][dst0 + 512] = vreg1;
    // ---- prefetch tile t+2 -> regs (issued ASAP; lands during next body) ----
    {
      const int tn = (t + 2 < S_ / 64) ? t + 2 : S_ / 64 - 1;
      const short* kp = ksrc + (size_t)tn * 64 * HD_;
      kreg0 = *(const bf16x8*)(kp);
      kreg1 = *(const bf16x8*)(kp + 32);
      const short* vp = vsrc + tn * 64;
      vreg0 = *(const bf16x8*)(vp);
      vreg1 = *(const bf16x8*)(vp + 32);
    }
    const short* ks = Ks[cur];
    const short* vt = Vt[cur];
    // ---- QK^T both groups (each kf read feeds 2 MFMAs); C-init = -mrow ----
    const f32x4 ciA = {nmA, nmA, nmA, nmA};
    const f32x4 ciB = {nmB, nmB, nmB, nmB};
    f32x4 scA[4], scB[4];
    __builtin_amdgcn_s_setprio(1);
#pragma unroll
    for (int nk = 0; nk < 4; ++nk) {
      f32x4 zA = ciA, zB = ciB;
#pragma unroll
      for (int k2 = 0; k2 < 2; ++k2) {
        bf16x8 kf = *(const bf16x8*)&ks[(nk * 2 + k2) * 512 + lane * 8];
        zA = __builtin_amdgcn_mfma_f32_16x16x32_bf16(kf, qfA[k2], zA, 0, 0, 0);
        zB = __builtin_amdgcn_mfma_f32_16x16x32_bf16(kf, qfB[k2], zB, 0, 0, 0);
      }
      scA[nk] = zA; scB[nk] = zB;
    }
    __builtin_amdgcn_s_setprio(0);
    // ---- per-lane max trees (off the exp path) ----
    float mxA = max3g(scA[0][0], scA[0][1], scA[0][2]);
    mxA = max3g(mxA, scA[0][3], scA[1][0]);
    mxA = max3g(mxA, scA[1][1], scA[1][2]);
    mxA = max3g(mxA, scA[1][3], scA[2][0]);
    mxA = max3g(mxA, scA[2][1], scA[2][2]);
    mxA = max3g(mxA, scA[2][3], scA[3][0]);
    mxA = max3g(mxA, scA[3][1], scA[3][2]);
    mxA = fmaxf(mxA, scA[3][3]);
    float mxB = max3g(scB[0][0], scB[0][1], scB[0][2]);
    mxB = max3g(mxB, scB[0][3], scB[1][0]);
    mxB = max3g(mxB, scB[1][1], scB[1][2]);
    mxB = max3g(mxB, scB[1][3], scB[2][0]);
    mxB = max3g(mxB, scB[2][1], scB[2][2]);
    mxB = max3g(mxB, scB[2][3], scB[3][0]);
    mxB = max3g(mxB, scB[3][1], scB[3][2]);
    mxB = fmaxf(mxB, scB[3][3]);
    // ---- speculative exp straight off the MFMA results (both groups) ----
#pragma unroll
    for (int nk = 0; nk < 4; ++nk)
#pragma unroll
      for (int r = 0; r < 4; ++r) {
        scA[nk][r] = exp2g(scA[nk][r]);
        scB[nk][r] = exp2g(scB[nk][r]);
      }
    if (!__all(fmaxf(mxA, mxB) <= 8.0f)) {   // rare fixup; alphas wave-uniform
      mxA = fmaxf(mxA, __shfl_xor(mxA, 16));
      mxA = fmaxf(mxA, __shfl_xor(mxA, 32));
      mxB = fmaxf(mxB, __shfl_xor(mxB, 16));
      mxB = fmaxf(mxB, __shfl_xor(mxB, 32));
      const float dA = fmaxf(mxA, 0.0f), dB = fmaxf(mxB, 0.0f);
      const float aA = exp2g(-dA), aB = exp2g(-dB);
      nmA -= dA; nmB -= dB;
#pragma unroll
      for (int nk = 0; nk < 4; ++nk)
#pragma unroll
        for (int r = 0; r < 4; ++r) { scA[nk][r] *= aA; scB[nk][r] *= aB; }
      accSA *= aA; accSB *= aB;
#pragma unroll
      for (int nd = 0; nd < 4; ++nd) { accA[nd] *= aA; accB[nd] *= aB; }
    }
    // ---- pack P into PV A-operands (perm pos = 32(nk&1)+8hi+4(nk>>1)+r) ----
    union PU { unsigned u[4]; bf16x8 v; } pA0, pA1, pB0, pB1;
    pA0.u[0] = cvtpk(scA[0][0], scA[0][1]); pA0.u[1] = cvtpk(scA[0][2], scA[0][3]);
    pA0.u[2] = cvtpk(scA[2][0], scA[2][1]); pA0.u[3] = cvtpk(scA[2][2], scA[2][3]);
    pA1.u[0] = cvtpk(scA[1][0], scA[1][1]); pA1.u[1] = cvtpk(scA[1][2], scA[1][3]);
    pA1.u[2] = cvtpk(scA[3][0], scA[3][1]); pA1.u[3] = cvtpk(scA[3][2], scA[3][3]);
    pB0.u[0] = cvtpk(scB[0][0], scB[0][1]); pB0.u[1] = cvtpk(scB[0][2], scB[0][3]);
    pB0.u[2] = cvtpk(scB[2][0], scB[2][1]); pB0.u[3] = cvtpk(scB[2][2], scB[2][3]);
    pB1.u[0] = cvtpk(scB[1][0], scB[1][1]); pB1.u[1] = cvtpk(scB[1][2], scB[1][3]);
    pB1.u[2] = cvtpk(scB[3][0], scB[3][1]); pB1.u[3] = cvtpk(scB[3][2], scB[3][3]);
    // ---- PV + row-sums (each vf read feeds 2 MFMAs) ----
    __builtin_amdgcn_s_setprio(1);
    accSA = __builtin_amdgcn_mfma_f32_16x16x32_bf16(pA0.v, onesf, accSA, 0, 0, 0);
    accSA = __builtin_amdgcn_mfma_f32_16x16x32_bf16(pA1.v, onesf, accSA, 0, 0, 0);
    accSB = __builtin_amdgcn_mfma_f32_16x16x32_bf16(pB0.v, onesf, accSB, 0, 0, 0);
    accSB = __builtin_amdgcn_mfma_f32_16x16x32_bf16(pB1.v, onesf, accSB, 0, 0, 0);
#pragma unroll
    for (int nd = 0; nd < 4; ++nd) {
      bf16x8 vf0 = *(const bf16x8*)&vt[(nd * 2 + 0) * 512 + lane * 8];
      accA[nd] = __builtin_amdgcn_mfma_f32_16x16x32_bf16(pA0.v, vf0, accA[nd], 0, 0, 0);
      accB[nd] = __builtin_amdgcn_mfma_f32_16x16x32_bf16(pB0.v, vf0, accB[nd], 0, 0, 0);
      bf16x8 vf1 = *(const bf16x8*)&vt[(nd * 2 + 1) * 512 + lane * 8];
      accA[nd] = __builtin_amdgcn_mfma_f32_16x16x32_bf16(pA1.v, vf1, accA[nd], 0, 0, 0);
      accB[nd] = __builtin_amdgcn_mfma_f32_16x16x32_bf16(pB1.v, vf1, accB[nd], 0, 0, 0);
    }
    __builtin_amdgcn_s_setprio(0);
    __syncthreads();                      // single barrier per tile
  }
  // ---- epilogue: O[q][d=16nd+lo]; l(q=4hi+r) = accS[r] @ lane hi*16 ----
#pragma unroll
  for (int r = 0; r < 4; ++r) {
    const float invA = rcpg(__shfl(accSA[r], hi << 4));
    const float invB = rcpg(__shfl(accSB[r], hi << 4));
    const int srA = q0 + hi * 4 + r;
    const size_t roA = ((size_t)bI * S_ + srA) * H_ + h * HD_;
    const size_t roB = ((size_t)bI * S_ + srA + 64) * H_ + h * HD_;
#pragma unroll
    for (int nd = 0; nd < 4; ++nd) {
      ctx[roA + nd * 16 + lo] = f2bf(accA[nd][r] * invA);
      ctx[roB + nd * 16 + lo] = f2bf(accB[nd][r] * invB);
    }
  }
}

// ---------------- launch -------------------------------------------------------
extern "C" void kernel_launch(void* const* d_in, const int* in_sizes, int n_in,
                              void* d_out, int out_size, void* d_ws, size_t ws_size,
                              hipStream_t stream) {
  const float* x    = (const float*)d_in[0];
  const float* ln1w = (const float*)d_in[1];
  const float* ln1b = (const float*)d_in[2];
  const float* wq   = (const float*)d_in[3];
  const float* bq   = (const float*)d_in[4];
  const float* wk   = (const float*)d_in[5];
  const float* bk   = (const float*)d_in[6];
  const float* wvp  = (const float*)d_in[7];
  const float* bv   = (const float*)d_in[8];
  const float* wo   = (const float*)d_in[9];
  const float* bo   = (const float*)d_in[10];
  const float* ln2w = (const float*)d_in[11];
  const float* ln2b = (const float*)d_in[12];
  const float* w1   = (const float*)d_in[13];
  const float* b1   = (const float*)d_in[14];
  const float* w2   = (const float*)d_in[15];
  const float* b2   = (const float*)d_in[16];
  float* out = (float*)d_out;

  short* ws = (short*)d_ws;
  short* wqkvT = ws;                              // [2304][768]
  short* woT   = wqkvT + (size_t)2304 * 768;      // [768][768]
  short* w1T   = woT + (size_t)768 * 768;         // [3072][768]
  short* w2T   = w1T + (size_t)3072 * 768;        // [768][3072]
  short* xn    = w2T + (size_t)768 * 3072;        // [8192][768] (reused as xn2)
  short* qb    = xn + (size_t)M_ * H_;            // [48][2048][64]
  short* kb    = qb + (size_t)M_ * H_;
  short* vb    = kb + (size_t)M_ * H_;            // V^T: [48][64][2048]
  short* ctx   = vb + (size_t)M_ * H_;            // [8192][768]
  short* yb    = qb;                              // reuse q..ctx: [8192][3072]
  float* x1    = (float*)(ctx + (size_t)M_ * H_); // [8192][768] fp32

  dim3 tb(32, 8);
  tcast4<<<dim3(24, 24, 4), tb, 0, stream>>>(wq, wk, wvp, wo,
      wqkvT, wqkvT + (size_t)768 * 768, wqkvT + (size_t)2 * 768 * 768, woT);
  tcast<<<dim3(96, 24), tb, 0, stream>>>(w1, w1T, 768, 3072);
  tcast<<<dim3(24, 96), tb, 0, stream>>>(w2, w2T, 3072, 768);

  ln_fwd<<<M_, 256, 0, stream>>>(x, ln1w, ln1b, xn);

  gemm_bt<0><<<dim3(36, 64), 256, 0, stream>>>(xn, wqkvT, 768, 2304,
      bq, bk, bv, nullptr, nullptr, nullptr, qb, kb, vb);

  attn_fwd<<<dim3(16, 48), 256, 0, stream>>>(qb, kb, vb, ctx);

  gemm_bt<1><<<dim3(12, 64), 256, 0, stream>>>(ctx, woT, 768, 768,
      bo, nullptr, nullptr, x, x1, nullptr, nullptr, nullptr, nullptr);

  ln_fwd<<<M_, 256, 0, stream>>>(x1, ln2w, ln2b, xn);

  gemm_bt<2><<<dim3(48, 64), 256, 0, stream>>>(xn, w1T, 768, 3072,
      b1, nullptr, nullptr, nullptr, nullptr, yb, nullptr, nullptr, nullptr);

  gemm_bt<1><<<dim3(12, 64), 256, 0, stream>>>(yb, w2T, 3072, 768,
      b2, nullptr, nullptr, x1, out, nullptr, nullptr, nullptr, nullptr);
}

// Round 15
// 282.571 us; speedup vs baseline: 1.2435x; 1.1926x over previous
//
#include <hip/hip_runtime.h>
#include <hip/hip_bf16.h>

#define B_ 4
#define S_ 2048
#define H_ 768
#define NH_ 12
#define HD_ 64
#define MLP_ 3072
#define M_ (B_*S_)

typedef float f32x4 __attribute__((ext_vector_type(4)));
typedef short bf16x8 __attribute__((ext_vector_type(8)));

__device__ __forceinline__ short f2bf(float f) {
  union { float f; unsigned u; } x; x.f = f;
  unsigned r = (x.u + 0x7fffu + ((x.u >> 16) & 1u)) >> 16;
  return (short)(unsigned short)r;
}

__device__ __forceinline__ float exp2g(float x) {   // raw v_exp_f32 (2^x)
  float r; asm("v_exp_f32 %0, %1" : "=v"(r) : "v"(x)); return r;
}
__device__ __forceinline__ float rcpg(float x) {    // raw v_rcp_f32
  float r; asm("v_rcp_f32 %0, %1" : "=v"(r) : "v"(x)); return r;
}
__device__ __forceinline__ float max3g(float a, float b, float c) {
  float r; asm("v_max3_f32 %0, %1, %2, %3" : "=v"(r) : "v"(a), "v"(b), "v"(c)); return r;
}
__device__ __forceinline__ unsigned cvtpk(float a, float b) { // [bf16(a)|bf16(b)<<16]
  unsigned r; asm("v_cvt_pk_bf16_f32 %0, %1, %2" : "=v"(r) : "v"(a), "v"(b)); return r;
}

typedef __attribute__((address_space(1))) const void gvoid;
typedef __attribute__((address_space(3))) void lvoid;
__device__ __forceinline__ void async16(const void* g, void* l) {
  __builtin_amdgcn_global_load_lds((gvoid*)g, (lvoid*)l, 16, 0, 0);
}

// bijective XCD chunk swizzle (m204): hw linear id -> logical id such that each
// XCD owns a CONTIGUOUS logical span (L2 locality for panel reuse).
__device__ __forceinline__ int xcd_swz(int h, int nwg) {
  const int q = nwg >> 3, r = nwg & 7;
  const int xc = h & 7, i = h >> 3;
  return (xc < r ? xc * (q + 1) : r * (q + 1) + (xc - r) * q) + i;
}

// ---------------- all weight transposes in ONE launch --------------------------
// out[n*K+k] = bf16(in[k*N+n]). Flat grid of 6912 blocks:
//   [0,2304):   four 768x768 (wq,wk,wv,wo), 576 blocks each (24x24)
//   [2304,4608): w1 [768][3072] -> w1T, 2304 blocks (96x24)
//   [4608,6912): w2 [3072][768] -> w2T, 2304 blocks (24x96)
__global__ __launch_bounds__(256)
void tcast_all(const float* __restrict__ wq, const float* __restrict__ wk,
               const float* __restrict__ wv, const float* __restrict__ wo,
               const float* __restrict__ w1, const float* __restrict__ w2,
               short* __restrict__ oq, short* __restrict__ ok,
               short* __restrict__ ov, short* __restrict__ oo,
               short* __restrict__ o1, short* __restrict__ o2) {
  __shared__ float tile[32][33];
  const int bid = blockIdx.x;
  const float* in; short* out; int K, N, bx, by;
  if (bid < 2304) {
    const int z = bid / 576, r = bid - z * 576;
    bx = r % 24; by = r / 24; K = 768; N = 768;
    in  = (z == 0) ? wq : (z == 1) ? wk : (z == 2) ? wv : wo;
    out = (z == 0) ? oq : (z == 1) ? ok : (z == 2) ? ov : oo;
  } else if (bid < 4608) {
    const int r = bid - 2304; bx = r % 96; by = r / 96; K = 768; N = 3072;
    in = w1; out = o1;
  } else {
    const int r = bid - 4608; bx = r % 24; by = r / 24; K = 3072; N = 768;
    in = w2; out = o2;
  }
  const int n0 = bx * 32, k0 = by * 32;
  const int tx = threadIdx.x, ty = threadIdx.y;
#pragma unroll
  for (int i = 0; i < 4; ++i)
    tile[ty * 4 + i][tx] = in[(size_t)(k0 + ty * 4 + i) * N + n0 + tx];
  __syncthreads();
#pragma unroll
  for (int i = 0; i < 4; ++i)
    out[(size_t)(n0 + ty * 4 + i) * K + k0 + tx] = f2bf(tile[tx][ty * 4 + i]);
}

// ---------------- layernorm (row of 768) -> bf16 ------------------------------
__device__ __forceinline__ float block_sum256(float v) {
  __shared__ float red[4];
#pragma unroll
  for (int o = 32; o > 0; o >>= 1) v += __shfl_down(v, o);
  if ((threadIdx.x & 63) == 0) red[threadIdx.x >> 6] = v;
  __syncthreads();
  v = red[0] + red[1] + red[2] + red[3];
  __syncthreads();
  return v;
}

__global__ __launch_bounds__(256)
void ln_fwd(const float* __restrict__ xin, const float* __restrict__ g,
            const float* __restrict__ bt, short* __restrict__ o) {
  const int row = blockIdx.x, t = threadIdx.x;
  const float* xr = xin + (size_t)row * H_;
  const float v0 = xr[t], v1 = xr[t + 256], v2 = xr[t + 512];
  const float mean = block_sum256(v0 + v1 + v2) * (1.0f / H_);
  const float d0 = v0 - mean, d1 = v1 - mean, d2 = v2 - mean;
  const float var = block_sum256(d0 * d0 + d1 * d1 + d2 * d2) * (1.0f / H_);
  const float rstd = rsqrtf(var + 1e-6f);
  short* orow = o + (size_t)row * H_;
  orow[t]       = f2bf(d0 * rstd * g[t] + bt[t]);
  orow[t + 256] = f2bf(d1 * rstd * g[t + 256] + bt[t + 256]);
  orow[t + 512] = f2bf(d2 * rstd * g[t + 512] + bt[t + 512]);
}

// ---------------- GEMM: C[M][N] = A[M][K](bf16) * Bw[N][K]^T(bf16) ------------
// r12-EXACT: 2-PHASE DOUBLE-BUFFERED (T3 minimum): one barrier per K-iter;
// next tile's global_load_lds issued right AFTER the barrier (flies under the
// current tile's MFMA). Tile 128x64, BK=64, LDS 48 KB -> 3 blocks/CU.
// XOR staging/read swizzle; XCD chunk swizzle (bn-fastest logical).
// [r13: 72KB 3-buf -> 2 blocks/CU, -22%. r14: BK=32 3-buf -> 8 MFMA/barrier,
//  -17%. Counted-vmcnt pipelines lose at this K; 2-phase is the verified best.]
#define QSCALE 0.18033688011112042f   /* 0.125 * log2(e) */
template<int MODE>
__global__ __launch_bounds__(256)
void gemm_bt(const short* __restrict__ A, const short* __restrict__ Bw,
             int K, int N,
             const float* __restrict__ b0, const float* __restrict__ b1,
             const float* __restrict__ b2,
             const float* __restrict__ resid,
             float* __restrict__ outf, short* __restrict__ outh,
             short* __restrict__ oq, short* __restrict__ ok2, short* __restrict__ ov) {
  __shared__ short As[2][128 * 64];
  __shared__ short Bs[2][64 * 64];
  const int tid = threadIdx.x;
  const int wv = tid >> 6, lane = tid & 63;
  const int lo = lane & 15, hi = lane >> 4;
  const int wr = wv >> 1, wc = wv & 1;

  const int GX = gridDim.x;
  const int logical = xcd_swz(blockIdx.y * GX + blockIdx.x, GX * gridDim.y);
  const int bn = logical % GX, bm = logical / GX;

  const short* Ab = A + (size_t)bm * 128 * K;
  const short* Bb = Bw + (size_t)bn * 64 * K;
  const int srow = lane >> 3;                 // row within 8-row staging call
  const int scol = ((lane & 7) ^ srow) * 8;   // pre-swizzled source col chunk

  auto stage = [&](int buf, int kt) {
#pragma unroll
    for (int c = 0; c < 4; ++c) {             // A: 32 rows/wave
      const int rb = wv * 32 + c * 8;
      async16(Ab + (size_t)(rb + srow) * K + kt + scol, &As[buf][rb * 64]);
    }
#pragma unroll
    for (int c = 0; c < 2; ++c) {             // B: 16 rows/wave
      const int rb = wv * 16 + c * 8;
      async16(Bb + (size_t)(rb + srow) * K + kt + scol, &Bs[buf][rb * 64]);
    }
  };

  f32x4 acc[4][2] = {};
  stage(0, 0);
  const int nIt = K >> 6;
  for (int it = 0; it < nIt; ++it) {
    __syncthreads();                          // drains stage of tile it; syncs buffers
    if (it + 1 < nIt) stage((it + 1) & 1, (it + 1) << 6);   // flies under MFMA below
    const short* as = As[it & 1];
    const short* bs = Bs[it & 1];
#pragma unroll
    for (int ks = 0; ks < 2; ++ks) {
      const int rc = (((ks * 4 + hi) ^ (lo & 7)) * 8);  // swizzled read chunk
      bf16x8 af[4], bfr[2];
#pragma unroll
      for (int m = 0; m < 4; ++m)
        af[m] = *(const bf16x8*)&as[(wr * 64 + m * 16 + lo) * 64 + rc];
#pragma unroll
      for (int n = 0; n < 2; ++n)
        bfr[n] = *(const bf16x8*)&bs[(wc * 32 + n * 16 + lo) * 64 + rc];
#pragma unroll
      for (int m = 0; m < 4; ++m)
#pragma unroll
        for (int n = 0; n < 2; ++n)
          acc[m][n] = __builtin_amdgcn_mfma_f32_16x16x32_bf16(af[m], bfr[n], acc[m][n], 0, 0, 0);
    }
  }
  const int colBase = bn * 64 + wc * 32;
  const int rowBase = bm * 128 + wr * 64;
#pragma unroll
  for (int m = 0; m < 4; ++m) {
#pragma unroll
    for (int n = 0; n < 2; ++n) {
#pragma unroll
      for (int r = 0; r < 4; ++r) {
        const int row = rowBase + m * 16 + hi * 4 + r;
        const int col = colBase + n * 16 + lo;
        float val = acc[m][n][r];
        if (MODE == 0) {
          const int which = col / H_;
          const int nn = col - which * H_;
          val += (which == 0 ? b0 : which == 1 ? b1 : b2)[nn];
          if (which == 0) val *= QSCALE;   // fold softmax scale + log2e into Q
          const int h = nn >> 6, d = nn & 63;
          const int bI = row >> 11, s = row & (S_ - 1);
          const short bv16 = f2bf(val);
          if (which == 2) {   // V^T layout, key-permuted within 64-blocks
            const int sl = s & 63;
            const int pc = ((sl >> 4) & 1) * 32 + ((sl >> 2) & 3) * 8
                         + ((sl >> 5) & 1) * 4 + (sl & 3);
            ov[(((size_t)bI * NH_ + h) * HD_ + d) * S_ + (s & ~63) + pc] = bv16;
          } else {
            short* dst = (which == 0 ? oq : ok2);
            dst[(((size_t)bI * NH_ + h) * S_ + s) * HD_ + d] = bv16;
          }
        } else if (MODE == 1) {
          val += b0[col] + resid[(size_t)row * N + col];
          outf[(size_t)row * N + col] = val;
        } else {
          val += b0[col];
          // tanh-gelu: x * sigmoid(2u), u = 0.79788456(x + 0.044715 x^3)
          const float u = val * (0.7978845608f + 0.0356774081f * val * val);
          const float e = exp2g(-2.885390082f * u);   // exp(-2u)
          val = val * rcpg(1.0f + e);
          outh[(size_t)row * N + col] = f2bf(val);
        }
      }
    }
  }
}

// ---------------- flash attention (swapped QK^T, P in registers, 2 q-groups) ---
// grid (S/128, B*NH) with XCD chunk swizzle. 4 waves; each wave handles TWO
// q-groups (rows q0..q0+15, q0+64..q0+79). Single barrier/tile, double-buffered
// K/V LDS. Stage-write + t+2 prefetch hoisted above QK^T. QK^T as mfma(K,Q)
// with C-init = -mrow; per-lane max3 tree gates rare wave-uniform fixup; l via
// ones-column MFMA; P in registers (cvtpk pack IS the PV A-operand; V^T
// key-permuted per 64-block).
__global__ __launch_bounds__(256)
void attn_fwd(const short* __restrict__ qbuf, const short* __restrict__ kbuf,
              const short* __restrict__ vbuf, short* __restrict__ ctx) {
  __shared__ short Ks[2][8 * 512];
  __shared__ short Vt[2][8 * 512];
  const int tid = threadIdx.x;
  const int wv = tid >> 6, lane = tid & 63;
  const int lo = lane & 15, hi = lane >> 4;
  const int logical = xcd_swz(blockIdx.y * 16 + blockIdx.x, 16 * 48);
  const int qt = logical & 15, bh = logical >> 4;
  const int bI = bh / NH_, h = bh - bI * NH_;
  const size_t baseBH = (size_t)bh * S_ * HD_;
  const int q0 = qt * 128 + wv * 16;       // group A; group B = q0 + 64

  bf16x8 qfA[2], qfB[2];  // B-operand: Q[qrow][d = k2*32 + hi*8 ..+7]
#pragma unroll
  for (int k2 = 0; k2 < 2; ++k2) {
    qfA[k2] = *(const bf16x8*)&qbuf[baseBH + (size_t)(q0 + lo) * HD_ + k2 * 32 + hi * 8];
    qfB[k2] = *(const bf16x8*)&qbuf[baseBH + (size_t)(q0 + 64 + lo) * HD_ + k2 * 32 + hi * 8];
  }

  f32x4 accA[4] = {}, accB[4] = {};
  f32x4 accSA = {}, accSB = {};         // row-sums via ones-column MFMA
  float nmA = 0.0f, nmB = 0.0f;         // -mrow per group

  // ones B-fragment: column 0 all ones -> C[:,0] = row-sum of A
  const short oo = (lo == 0) ? (short)0x3F80 : (short)0;
  const bf16x8 onesf = {oo, oo, oo, oo, oo, oo, oo, oo};

  // staging: wave wv owns frags {2wv,2wv+1} of K and V (contiguous 16B/lane).
  const short* ksrc = kbuf + baseBH + (size_t)(wv * 16 + lo) * HD_ + hi * 8;
  const short* vsrc = vbuf + baseBH + (size_t)(wv * 16 + lo) * S_ + hi * 8;
  const int dst0 = wv * 1024 + lane * 8;

  bf16x8 kreg0, kreg1, vreg0, vreg1;
  // tile 0 -> regs -> buf0
  kreg0 = *(const bf16x8*)(ksrc);
  kreg1 = *(const bf16x8*)(ksrc + 32);
  vreg0 = *(const bf16x8*)(vsrc);
  vreg1 = *(const bf16x8*)(vsrc + 32);
  *(bf16x8*)&Ks[0][dst0] = kreg0;
  *(bf16x8*)&Ks[0][dst0 + 512] = kreg1;
  *(bf16x8*)&Vt[0][dst0] = vreg0;
  *(bf16x8*)&Vt[0][dst0 + 512] = vreg1;
  // tile 1 -> regs
  kreg0 = *(const bf16x8*)(ksrc + (size_t)64 * HD_);
  kreg1 = *(const bf16x8*)(ksrc + (size_t)64 * HD_ + 32);
  vreg0 = *(const bf16x8*)(vsrc + 64);
  vreg1 = *(const bf16x8*)(vsrc + 64 + 32);
  __syncthreads();

  for (int t = 0; t < S_ / 64; ++t) {
    const int cur = t & 1, nxt = cur ^ 1;
    // ---- stage tile t+1 regs -> spare buffer (safe: barrier(t-1) passed) ----
    *(bf16x8*)&Ks[nxt][dst0] = kreg0;
    *(bf16x8*)&Ks[nxt][dst0 + 512] = kreg1;
    *(bf16x8*)&Vt[nxt][dst0] = vreg0;
    *(bf16x8*)&Vt[nxt][dst0 + 512] = vreg1;
    // ---- prefetch tile t+2 -> regs (issued ASAP; lands during next body) ----
    {
      const int tn = (t + 2 < S_ / 64) ? t + 2 : S_ / 64 - 1;
      const short* kp = ksrc + (size_t)tn * 64 * HD_;
      kreg0 = *(const bf16x8*)(kp);
      kreg1 = *(const bf16x8*)(kp + 32);
      const short* vp = vsrc + tn * 64;
      vreg0 = *(const bf16x8*)(vp);
      vreg1 = *(const bf16x8*)(vp + 32);
    }
    const short* ks = Ks[cur];
    const short* vt = Vt[cur];
    // ---- QK^T both groups (each kf read feeds 2 MFMAs); C-init = -mrow ----
    const f32x4 ciA = {nmA, nmA, nmA, nmA};
    const f32x4 ciB = {nmB, nmB, nmB, nmB};
    f32x4 scA[4], scB[4];
    __builtin_amdgcn_s_setprio(1);
#pragma unroll
    for (int nk = 0; nk < 4; ++nk) {
      f32x4 zA = ciA, zB = ciB;
#pragma unroll
      for (int k2 = 0; k2 < 2; ++k2) {
        bf16x8 kf = *(const bf16x8*)&ks[(nk * 2 + k2) * 512 + lane * 8];
        zA = __builtin_amdgcn_mfma_f32_16x16x32_bf16(kf, qfA[k2], zA, 0, 0, 0);
        zB = __builtin_amdgcn_mfma_f32_16x16x32_bf16(kf, qfB[k2], zB, 0, 0, 0);
      }
      scA[nk] = zA; scB[nk] = zB;
    }
    __builtin_amdgcn_s_setprio(0);
    // ---- per-lane max trees (off the exp path) ----
    float mxA = max3g(scA[0][0], scA[0][1], scA[0][2]);
    mxA = max3g(mxA, scA[0][3], scA[1][0]);
    mxA = max3g(mxA, scA[1][1], scA[1][2]);
    mxA = max3g(mxA, scA[1][3], scA[2][0]);
    mxA = max3g(mxA, scA[2][1], scA[2][2]);
    mxA = max3g(mxA, scA[2][3], scA[3][0]);
    mxA = max3g(mxA, scA[3][1], scA[3][2]);
    mxA = fmaxf(mxA, scA[3][3]);
    float mxB = max3g(scB[0][0], scB[0][1], scB[0][2]);
    mxB = max3g(mxB, scB[0][3], scB[1][0]);
    mxB = max3g(mxB, scB[1][1], scB[1][2]);
    mxB = max3g(mxB, scB[1][3], scB[2][0]);
    mxB = max3g(mxB, scB[2][1], scB[2][2]);
    mxB = max3g(mxB, scB[2][3], scB[3][0]);
    mxB = max3g(mxB, scB[3][1], scB[3][2]);
    mxB = fmaxf(mxB, scB[3][3]);
    // ---- speculative exp straight off the MFMA results (both groups) ----
#pragma unroll
    for (int nk = 0; nk < 4; ++nk)
#pragma unroll
      for (int r = 0; r < 4; ++r) {
        scA[nk][r] = exp2g(scA[nk][r]);
        scB[nk][r] = exp2g(scB[nk][r]);
      }
    if (!__all(fmaxf(mxA, mxB) <= 8.0f)) {   // rare fixup; alphas wave-uniform
      mxA = fmaxf(mxA, __shfl_xor(mxA, 16));
      mxA = fmaxf(mxA, __shfl_xor(mxA, 32));
      mxB = fmaxf(mxB, __shfl_xor(mxB, 16));
      mxB = fmaxf(mxB, __shfl_xor(mxB, 32));
      const float dA = fmaxf(mxA, 0.0f), dB = fmaxf(mxB, 0.0f);
      const float aA = exp2g(-dA), aB = exp2g(-dB);
      nmA -= dA; nmB -= dB;
#pragma unroll
      for (int nk = 0; nk < 4; ++nk)
#pragma unroll
        for (int r = 0; r < 4; ++r) { scA[nk][r] *= aA; scB[nk][r] *= aB; }
      accSA *= aA; accSB *= aB;
#pragma unroll
      for (int nd = 0; nd < 4; ++nd) { accA[nd] *= aA; accB[nd] *= aB; }
    }
    // ---- pack P into PV A-operands (perm pos = 32(nk&1)+8hi+4(nk>>1)+r) ----
    union PU { unsigned u[4]; bf16x8 v; } pA0, pA1, pB0, pB1;
    pA0.u[0] = cvtpk(scA[0][0], scA[0][1]); pA0.u[1] = cvtpk(scA[0][2], scA[0][3]);
    pA0.u[2] = cvtpk(scA[2][0], scA[2][1]); pA0.u[3] = cvtpk(scA[2][2], scA[2][3]);
    pA1.u[0] = cvtpk(scA[1][0], scA[1][1]); pA1.u[1] = cvtpk(scA[1][2], scA[1][3]);
    pA1.u[2] = cvtpk(scA[3][0], scA[3][1]); pA1.u[3] = cvtpk(scA[3][2], scA[3][3]);
    pB0.u[0] = cvtpk(scB[0][0], scB[0][1]); pB0.u[1] = cvtpk(scB[0][2], scB[0][3]);
    pB0.u[2] = cvtpk(scB[2][0], scB[2][1]); pB0.u[3] = cvtpk(scB[2][2], scB[2][3]);
    pB1.u[0] = cvtpk(scB[1][0], scB[1][1]); pB1.u[1] = cvtpk(scB[1][2], scB[1][3]);
    pB1.u[2] = cvtpk(scB[3][0], scB[3][1]); pB1.u[3] = cvtpk(scB[3][2], scB[3][3]);
    // ---- PV + row-sums (each vf read feeds 2 MFMAs) ----
    __builtin_amdgcn_s_setprio(1);
    accSA = __builtin_amdgcn_mfma_f32_16x16x32_bf16(pA0.v, onesf, accSA, 0, 0, 0);
    accSA = __builtin_amdgcn_mfma_f32_16x16x32_bf16(pA1.v, onesf, accSA, 0, 0, 0);
    accSB = __builtin_amdgcn_mfma_f32_16x16x32_bf16(pB0.v, onesf, accSB, 0, 0, 0);
    accSB = __builtin_amdgcn_mfma_f32_16x16x32_bf16(pB1.v, onesf, accSB, 0, 0, 0);
#pragma unroll
    for (int nd = 0; nd < 4; ++nd) {
      bf16x8 vf0 = *(const bf16x8*)&vt[(nd * 2 + 0) * 512 + lane * 8];
      accA[nd] = __builtin_amdgcn_mfma_f32_16x16x32_bf16(pA0.v, vf0, accA[nd], 0, 0, 0);
      accB[nd] = __builtin_amdgcn_mfma_f32_16x16x32_bf16(pB0.v, vf0, accB[nd], 0, 0, 0);
      bf16x8 vf1 = *(const bf16x8*)&vt[(nd * 2 + 1) * 512 + lane * 8];
      accA[nd] = __builtin_amdgcn_mfma_f32_16x16x32_bf16(pA1.v, vf1, accA[nd], 0, 0, 0);
      accB[nd] = __builtin_amdgcn_mfma_f32_16x16x32_bf16(pB1.v, vf1, accB[nd], 0, 0, 0);
    }
    __builtin_amdgcn_s_setprio(0);
    __syncthreads();                      // single barrier per tile
  }
  // ---- epilogue: O[q][d=16nd+lo]; l(q=4hi+r) = accS[r] @ lane hi*16 ----
#pragma unroll
  for (int r = 0; r < 4; ++r) {
    const float invA = rcpg(__shfl(accSA[r], hi << 4));
    const float invB = rcpg(__shfl(accSB[r], hi << 4));
    const int srA = q0 + hi * 4 + r;
    const size_t roA = ((size_t)bI * S_ + srA) * H_ + h * HD_;
    const size_t roB = ((size_t)bI * S_ + srA + 64) * H_ + h * HD_;
#pragma unroll
    for (int nd = 0; nd < 4; ++nd) {
      ctx[roA + nd * 16 + lo] = f2bf(accA[nd][r] * invA);
      ctx[roB + nd * 16 + lo] = f2bf(accB[nd][r] * invB);
    }
  }
}

// ---------------- launch -------------------------------------------------------
extern "C" void kernel_launch(void* const* d_in, const int* in_sizes, int n_in,
                              void* d_out, int out_size, void* d_ws, size_t ws_size,
                              hipStream_t stream) {
  const float* x    = (const float*)d_in[0];
  const float* ln1w = (const float*)d_in[1];
  const float* ln1b = (const float*)d_in[2];
  const float* wq   = (const float*)d_in[3];
  const float* bq   = (const float*)d_in[4];
  const float* wk   = (const float*)d_in[5];
  const float* bk   = (const float*)d_in[6];
  const float* wvp  = (const float*)d_in[7];
  const float* bv   = (const float*)d_in[8];
  const float* wo   = (const float*)d_in[9];
  const float* bo   = (const float*)d_in[10];
  const float* ln2w = (const float*)d_in[11];
  const float* ln2b = (const float*)d_in[12];
  const float* w1   = (const float*)d_in[13];
  const float* b1   = (const float*)d_in[14];
  const float* w2   = (const float*)d_in[15];
  const float* b2   = (const float*)d_in[16];
  float* out = (float*)d_out;

  short* ws = (short*)d_ws;
  short* wqkvT = ws;                              // [2304][768]
  short* woT   = wqkvT + (size_t)2304 * 768;      // [768][768]
  short* w1T   = woT + (size_t)768 * 768;         // [3072][768]
  short* w2T   = w1T + (size_t)3072 * 768;        // [768][3072]
  short* xn    = w2T + (size_t)768 * 3072;        // [8192][768] (reused as xn2)
  short* qb    = xn + (size_t)M_ * H_;            // [48][2048][64]
  short* kb    = qb + (size_t)M_ * H_;
  short* vb    = kb + (size_t)M_ * H_;            // V^T: [48][64][2048]
  short* ctx   = vb + (size_t)M_ * H_;            // [8192][768]
  short* yb    = qb;                              // reuse q..ctx: [8192][3072]
  float* x1    = (float*)(ctx + (size_t)M_ * H_); // [8192][768] fp32

  tcast_all<<<6912, dim3(32, 8), 0, stream>>>(wq, wk, wvp, wo, w1, w2,
      wqkvT, wqkvT + (size_t)768 * 768, wqkvT + (size_t)2 * 768 * 768, woT,
      w1T, w2T);

  ln_fwd<<<M_, 256, 0, stream>>>(x, ln1w, ln1b, xn);

  gemm_bt<0><<<dim3(36, 64), 256, 0, stream>>>(xn, wqkvT, 768, 2304,
      bq, bk, bv, nullptr, nullptr, nullptr, qb, kb, vb);

  attn_fwd<<<dim3(16, 48), 256, 0, stream>>>(qb, kb, vb, ctx);

  gemm_bt<1><<<dim3(12, 64), 256, 0, stream>>>(ctx, woT, 768, 768,
      bo, nullptr, nullptr, x, x1, nullptr, nullptr, nullptr, nullptr);

  ln_fwd<<<M_, 256, 0, stream>>>(x1, ln2w, ln2b, xn);

  gemm_bt<2><<<dim3(48, 64), 256, 0, stream>>>(xn, w1T, 768, 3072,
      b1, nullptr, nullptr, nullptr, nullptr, yb, nullptr, nullptr, nullptr);

  gemm_bt<1><<<dim3(12, 64), 256, 0, stream>>>(yb, w2T, 3072, 768,
      b2, nullptr, nullptr, x1, out, nullptr, nullptr, nullptr, nullptr);
}

// Round 16
// 277.801 us; speedup vs baseline: 1.2649x; 1.0172x over previous
//
#include <hip/hip_runtime.h>
#include <hip/hip_bf16.h>

#define B_ 4
#define S_ 2048
#define H_ 768
#define NH_ 12
#define HD_ 64
#define MLP_ 3072
#define M_ (B_*S_)

typedef float f32x4 __attribute__((ext_vector_type(4)));
typedef short bf16x8 __attribute__((ext_vector_type(8)));

__device__ __forceinline__ short f2bf(float f) {
  union { float f; unsigned u; } x; x.f = f;
  unsigned r = (x.u + 0x7fffu + ((x.u >> 16) & 1u)) >> 16;
  return (short)(unsigned short)r;
}

__device__ __forceinline__ float exp2g(float x) {   // raw v_exp_f32 (2^x)
  float r; asm("v_exp_f32 %0, %1" : "=v"(r) : "v"(x)); return r;
}
__device__ __forceinline__ float rcpg(float x) {    // raw v_rcp_f32
  float r; asm("v_rcp_f32 %0, %1" : "=v"(r) : "v"(x)); return r;
}
__device__ __forceinline__ float max3g(float a, float b, float c) {
  float r; asm("v_max3_f32 %0, %1, %2, %3" : "=v"(r) : "v"(a), "v"(b), "v"(c)); return r;
}
__device__ __forceinline__ unsigned cvtpk(float a, float b) { // [bf16(a)|bf16(b)<<16]
  unsigned r; asm("v_cvt_pk_bf16_f32 %0, %1, %2" : "=v"(r) : "v"(a), "v"(b)); return r;
}

typedef __attribute__((address_space(1))) const void gvoid;
typedef __attribute__((address_space(3))) void lvoid;
__device__ __forceinline__ void async16(const void* g, void* l) {
  __builtin_amdgcn_global_load_lds((gvoid*)g, (lvoid*)l, 16, 0, 0);
}

// bijective XCD chunk swizzle (m204): hw linear id -> logical id such that each
// XCD owns a CONTIGUOUS logical span (L2 locality for panel reuse).
__device__ __forceinline__ int xcd_swz(int h, int nwg) {
  const int q = nwg >> 3, r = nwg & 7;
  const int xc = h & 7, i = h >> 3;
  return (xc < r ? xc * (q + 1) : r * (q + 1) + (xc - r) * q) + i;
}

// ---------------- all weight transposes in ONE launch --------------------------
__global__ __launch_bounds__(256)
void tcast_all(const float* __restrict__ wq, const float* __restrict__ wk,
               const float* __restrict__ wv, const float* __restrict__ wo,
               const float* __restrict__ w1, const float* __restrict__ w2,
               short* __restrict__ oq, short* __restrict__ ok,
               short* __restrict__ ov, short* __restrict__ oo,
               short* __restrict__ o1, short* __restrict__ o2) {
  __shared__ float tile[32][33];
  const int bid = blockIdx.x;
  const float* in; short* out; int K, N, bx, by;
  if (bid < 2304) {
    const int z = bid / 576, r = bid - z * 576;
    bx = r % 24; by = r / 24; K = 768; N = 768;
    in  = (z == 0) ? wq : (z == 1) ? wk : (z == 2) ? wv : wo;
    out = (z == 0) ? oq : (z == 1) ? ok : (z == 2) ? ov : oo;
  } else if (bid < 4608) {
    const int r = bid - 2304; bx = r % 96; by = r / 96; K = 768; N = 3072;
    in = w1; out = o1;
  } else {
    const int r = bid - 4608; bx = r % 24; by = r / 24; K = 3072; N = 768;
    in = w2; out = o2;
  }
  const int n0 = bx * 32, k0 = by * 32;
  const int tx = threadIdx.x, ty = threadIdx.y;
#pragma unroll
  for (int i = 0; i < 4; ++i)
    tile[ty * 4 + i][tx] = in[(size_t)(k0 + ty * 4 + i) * N + n0 + tx];
  __syncthreads();
#pragma unroll
  for (int i = 0; i < 4; ++i)
    out[(size_t)(n0 + ty * 4 + i) * K + k0 + tx] = f2bf(tile[tx][ty * 4 + i]);
}

// ---------------- layernorm (row of 768) -> bf16 ------------------------------
__device__ __forceinline__ float block_sum256(float v) {
  __shared__ float red[4];
#pragma unroll
  for (int o = 32; o > 0; o >>= 1) v += __shfl_down(v, o);
  if ((threadIdx.x & 63) == 0) red[threadIdx.x >> 6] = v;
  __syncthreads();
  v = red[0] + red[1] + red[2] + red[3];
  __syncthreads();
  return v;
}

__global__ __launch_bounds__(256)
void ln_fwd(const float* __restrict__ xin, const float* __restrict__ g,
            const float* __restrict__ bt, short* __restrict__ o) {
  const int row = blockIdx.x, t = threadIdx.x;
  const float* xr = xin + (size_t)row * H_;
  const float v0 = xr[t], v1 = xr[t + 256], v2 = xr[t + 512];
  const float mean = block_sum256(v0 + v1 + v2) * (1.0f / H_);
  const float d0 = v0 - mean, d1 = v1 - mean, d2 = v2 - mean;
  const float var = block_sum256(d0 * d0 + d1 * d1 + d2 * d2) * (1.0f / H_);
  const float rstd = rsqrtf(var + 1e-6f);
  short* orow = o + (size_t)row * H_;
  orow[t]       = f2bf(d0 * rstd * g[t] + bt[t]);
  orow[t + 256] = f2bf(d1 * rstd * g[t + 256] + bt[t + 256]);
  orow[t + 512] = f2bf(d2 * rstd * g[t + 512] + bt[t + 512]);
}

#define QSCALE 0.18033688011112042f   /* 0.125 * log2(e) */

// ---------------- 4-wave GEMM (TN=64) — r12-exact, for proj/MLP2 (N=768) ------
template<int MODE>
__global__ __launch_bounds__(256)
void gemm_bt(const short* __restrict__ A, const short* __restrict__ Bw,
             int K, int N,
             const float* __restrict__ b0,
             const float* __restrict__ resid,
             float* __restrict__ outf, short* __restrict__ outh) {
  __shared__ short As[2][128 * 64];
  __shared__ short Bs[2][64 * 64];
  const int tid = threadIdx.x;
  const int wv = tid >> 6, lane = tid & 63;
  const int lo = lane & 15, hi = lane >> 4;
  const int wr = wv >> 1, wc = wv & 1;

  const int GX = gridDim.x;
  const int logical = xcd_swz(blockIdx.y * GX + blockIdx.x, GX * gridDim.y);
  const int bn = logical % GX, bm = logical / GX;

  const short* Ab = A + (size_t)bm * 128 * K;
  const short* Bb = Bw + (size_t)bn * 64 * K;
  const int srow = lane >> 3;                 // row within 8-row staging call
  const int scol = ((lane & 7) ^ srow) * 8;   // pre-swizzled source col chunk

  auto stage = [&](int buf, int kt) {
#pragma unroll
    for (int c = 0; c < 4; ++c) {             // A: 32 rows/wave
      const int rb = wv * 32 + c * 8;
      async16(Ab + (size_t)(rb + srow) * K + kt + scol, &As[buf][rb * 64]);
    }
#pragma unroll
    for (int c = 0; c < 2; ++c) {             // B: 16 rows/wave
      const int rb = wv * 16 + c * 8;
      async16(Bb + (size_t)(rb + srow) * K + kt + scol, &Bs[buf][rb * 64]);
    }
  };

  f32x4 acc[4][2] = {};
  stage(0, 0);
  const int nIt = K >> 6;
  for (int it = 0; it < nIt; ++it) {
    __syncthreads();
    if (it + 1 < nIt) stage((it + 1) & 1, (it + 1) << 6);
    const short* as = As[it & 1];
    const short* bs = Bs[it & 1];
#pragma unroll
    for (int ks = 0; ks < 2; ++ks) {
      const int rc = (((ks * 4 + hi) ^ (lo & 7)) * 8);
      bf16x8 af[4], bfr[2];
#pragma unroll
      for (int m = 0; m < 4; ++m)
        af[m] = *(const bf16x8*)&as[(wr * 64 + m * 16 + lo) * 64 + rc];
#pragma unroll
      for (int n = 0; n < 2; ++n)
        bfr[n] = *(const bf16x8*)&bs[(wc * 32 + n * 16 + lo) * 64 + rc];
#pragma unroll
      for (int m = 0; m < 4; ++m)
#pragma unroll
        for (int n = 0; n < 2; ++n)
          acc[m][n] = __builtin_amdgcn_mfma_f32_16x16x32_bf16(af[m], bfr[n], acc[m][n], 0, 0, 0);
    }
  }
  const int colBase = bn * 64 + wc * 32;
  const int rowBase = bm * 128 + wr * 64;
#pragma unroll
  for (int m = 0; m < 4; ++m) {
#pragma unroll
    for (int n = 0; n < 2; ++n) {
#pragma unroll
      for (int r = 0; r < 4; ++r) {
        const int row = rowBase + m * 16 + hi * 4 + r;
        const int col = colBase + n * 16 + lo;
        float val = acc[m][n][r] + b0[col];
        if (MODE == 1) {
          val += resid[(size_t)row * N + col];
          outf[(size_t)row * N + col] = val;
        } else {
          const float u = val * (0.7978845608f + 0.0356774081f * val * val);
          const float e = exp2g(-2.885390082f * u);
          val = val * rcpg(1.0f + e);
          outh[(size_t)row * N + col] = f2bf(val);
        }
      }
    }
  }
}

// ---------------- 8-wave GEMM (TN=128) — same 2-phase schedule; QKV/MLP1 ------
// 512 threads, tile 128x128, BK=64, LDS 64 KB -> 2 blocks/CU = 16 waves/CU
// (4/SIMD, +33% TLP vs 4-wave). Staging 4 async16/wave/iter (vs 6), MFMA/wave
// unchanged (16/iter). Wave grid wr=wv>>2 (2 rows of 64), wc=wv&3 (4 cols of 32).
// MODE 0: QKV scatter; MODE 2: +bias tanh-gelu.
template<int MODE>
__global__ __launch_bounds__(512)
void gemm_bt8(const short* __restrict__ A, const short* __restrict__ Bw,
              int K, int N,
              const float* __restrict__ b0, const float* __restrict__ b1,
              const float* __restrict__ b2,
              short* __restrict__ outh,
              short* __restrict__ oq, short* __restrict__ ok2, short* __restrict__ ov) {
  __shared__ short As[2][128 * 64];
  __shared__ short Bs[2][128 * 64];
  const int tid = threadIdx.x;
  const int wv = tid >> 6, lane = tid & 63;
  const int lo = lane & 15, hi = lane >> 4;
  const int wr = wv >> 2, wc = wv & 3;

  const int GX = gridDim.x;
  const int logical = xcd_swz(blockIdx.y * GX + blockIdx.x, GX * gridDim.y);
  const int bn = logical % GX, bm = logical / GX;

  const short* Ab = A + (size_t)bm * 128 * K;
  const short* Bb = Bw + (size_t)bn * 128 * K;
  const int srow = lane >> 3;
  const int scol = ((lane & 7) ^ srow) * 8;

  auto stage = [&](int buf, int kt) {
#pragma unroll
    for (int c = 0; c < 2; ++c) {             // A: 16 rows/wave, 2 calls
      const int rb = wv * 16 + c * 8;
      async16(Ab + (size_t)(rb + srow) * K + kt + scol, &As[buf][rb * 64]);
    }
#pragma unroll
    for (int c = 0; c < 2; ++c) {             // B: 16 rows/wave, 2 calls
      const int rb = wv * 16 + c * 8;
      async16(Bb + (size_t)(rb + srow) * K + kt + scol, &Bs[buf][rb * 64]);
    }
  };

  f32x4 acc[4][2] = {};
  stage(0, 0);
  const int nIt = K >> 6;
  for (int it = 0; it < nIt; ++it) {
    __syncthreads();
    if (it + 1 < nIt) stage((it + 1) & 1, (it + 1) << 6);
    const short* as = As[it & 1];
    const short* bs = Bs[it & 1];
#pragma unroll
    for (int ks = 0; ks < 2; ++ks) {
      const int rc = (((ks * 4 + hi) ^ (lo & 7)) * 8);
      bf16x8 af[4], bfr[2];
#pragma unroll
      for (int m = 0; m < 4; ++m)
        af[m] = *(const bf16x8*)&as[(wr * 64 + m * 16 + lo) * 64 + rc];
#pragma unroll
      for (int n = 0; n < 2; ++n)
        bfr[n] = *(const bf16x8*)&bs[(wc * 32 + n * 16 + lo) * 64 + rc];
#pragma unroll
      for (int m = 0; m < 4; ++m)
#pragma unroll
        for (int n = 0; n < 2; ++n)
          acc[m][n] = __builtin_amdgcn_mfma_f32_16x16x32_bf16(af[m], bfr[n], acc[m][n], 0, 0, 0);
    }
  }
  const int colBase = bn * 128 + wc * 32;
  const int rowBase = bm * 128 + wr * 64;
#pragma unroll
  for (int m = 0; m < 4; ++m) {
#pragma unroll
    for (int n = 0; n < 2; ++n) {
#pragma unroll
      for (int r = 0; r < 4; ++r) {
        const int row = rowBase + m * 16 + hi * 4 + r;
        const int col = colBase + n * 16 + lo;
        float val = acc[m][n][r];
        if (MODE == 0) {
          const int which = col / H_;
          const int nn = col - which * H_;
          val += (which == 0 ? b0 : which == 1 ? b1 : b2)[nn];
          if (which == 0) val *= QSCALE;
          const int h = nn >> 6, d = nn & 63;
          const int bI = row >> 11, s = row & (S_ - 1);
          const short bv16 = f2bf(val);
          if (which == 2) {   // V^T layout, key-permuted within 64-blocks
            const int sl = s & 63;
            const int pc = ((sl >> 4) & 1) * 32 + ((sl >> 2) & 3) * 8
                         + ((sl >> 5) & 1) * 4 + (sl & 3);
            ov[(((size_t)bI * NH_ + h) * HD_ + d) * S_ + (s & ~63) + pc] = bv16;
          } else {
            short* dst = (which == 0 ? oq : ok2);
            dst[(((size_t)bI * NH_ + h) * S_ + s) * HD_ + d] = bv16;
          }
        } else {
          val += b0[col];
          const float u = val * (0.7978845608f + 0.0356774081f * val * val);
          const float e = exp2g(-2.885390082f * u);
          val = val * rcpg(1.0f + e);
          outh[(size_t)row * N + col] = f2bf(val);
        }
      }
    }
  }
}

// ---------------- flash attention (swapped QK^T, P in registers, 2 q-groups) ---
__global__ __launch_bounds__(256)
void attn_fwd(const short* __restrict__ qbuf, const short* __restrict__ kbuf,
              const short* __restrict__ vbuf, short* __restrict__ ctx) {
  __shared__ short Ks[2][8 * 512];
  __shared__ short Vt[2][8 * 512];
  const int tid = threadIdx.x;
  const int wv = tid >> 6, lane = tid & 63;
  const int lo = lane & 15, hi = lane >> 4;
  const int logical = xcd_swz(blockIdx.y * 16 + blockIdx.x, 16 * 48);
  const int qt = logical & 15, bh = logical >> 4;
  const int bI = bh / NH_, h = bh - bI * NH_;
  const size_t baseBH = (size_t)bh * S_ * HD_;
  const int q0 = qt * 128 + wv * 16;       // group A; group B = q0 + 64

  bf16x8 qfA[2], qfB[2];
#pragma unroll
  for (int k2 = 0; k2 < 2; ++k2) {
    qfA[k2] = *(const bf16x8*)&qbuf[baseBH + (size_t)(q0 + lo) * HD_ + k2 * 32 + hi * 8];
    qfB[k2] = *(const bf16x8*)&qbuf[baseBH + (size_t)(q0 + 64 + lo) * HD_ + k2 * 32 + hi * 8];
  }

  f32x4 accA[4] = {}, accB[4] = {};
  f32x4 accSA = {}, accSB = {};
  float nmA = 0.0f, nmB = 0.0f;

  const short oo = (lo == 0) ? (short)0x3F80 : (short)0;
  const bf16x8 onesf = {oo, oo, oo, oo, oo, oo, oo, oo};

  const short* ksrc = kbuf + baseBH + (size_t)(wv * 16 + lo) * HD_ + hi * 8;
  const short* vsrc = vbuf + baseBH + (size_t)(wv * 16 + lo) * S_ + hi * 8;
  const int dst0 = wv * 1024 + lane * 8;

  bf16x8 kreg0, kreg1, vreg0, vreg1;
  kreg0 = *(const bf16x8*)(ksrc);
  kreg1 = *(const bf16x8*)(ksrc + 32);
  vreg0 = *(const bf16x8*)(vsrc);
  vreg1 = *(const bf16x8*)(vsrc + 32);
  *(bf16x8*)&Ks[0][dst0] = kreg0;
  *(bf16x8*)&Ks[0][dst0 + 512] = kreg1;
  *(bf16x8*)&Vt[0][dst0] = vreg0;
  *(bf16x8*)&Vt[0][dst0 + 512] = vreg1;
  kreg0 = *(const bf16x8*)(ksrc + (size_t)64 * HD_);
  kreg1 = *(const bf16x8*)(ksrc + (size_t)64 * HD_ + 32);
  vreg0 = *(const bf16x8*)(vsrc + 64);
  vreg1 = *(const bf16x8*)(vsrc + 64 + 32);
  __syncthreads();

  for (int t = 0; t < S_ / 64; ++t) {
    const int cur = t & 1, nxt = cur ^ 1;
    *(bf16x8*)&Ks[nxt][dst0] = kreg0;
    *(bf16x8*)&Ks[nxt][dst0 + 512] = kreg1;
    *(bf16x8*)&Vt[nxt][dst0] = vreg0;
    *(bf16x8*)&Vt[nxt][dst0 + 512] = vreg1;
    {
      const int tn = (t + 2 < S_ / 64) ? t + 2 : S_ / 64 - 1;
      const short* kp = ksrc + (size_t)tn * 64 * HD_;
      kreg0 = *(const bf16x8*)(kp);
      kreg1 = *(const bf16x8*)(kp + 32);
      const short* vp = vsrc + tn * 64;
      vreg0 = *(const bf16x8*)(vp);
      vreg1 = *(const bf16x8*)(vp + 32);
    }
    const short* ks = Ks[cur];
    const short* vt = Vt[cur];
    const f32x4 ciA = {nmA, nmA, nmA, nmA};
    const f32x4 ciB = {nmB, nmB, nmB, nmB};
    f32x4 scA[4], scB[4];
    __builtin_amdgcn_s_setprio(1);
#pragma unroll
    for (int nk = 0; nk < 4; ++nk) {
      f32x4 zA = ciA, zB = ciB;
#pragma unroll
      for (int k2 = 0; k2 < 2; ++k2) {
        bf16x8 kf = *(const bf16x8*)&ks[(nk * 2 + k2) * 512 + lane * 8];
        zA = __builtin_amdgcn_mfma_f32_16x16x32_bf16(kf, qfA[k2], zA, 0, 0, 0);
        zB = __builtin_amdgcn_mfma_f32_16x16x32_bf16(kf, qfB[k2], zB, 0, 0, 0);
      }
      scA[nk] = zA; scB[nk] = zB;
    }
    __builtin_amdgcn_s_setprio(0);
    float mxA = max3g(scA[0][0], scA[0][1], scA[0][2]);
    mxA = max3g(mxA, scA[0][3], scA[1][0]);
    mxA = max3g(mxA, scA[1][1], scA[1][2]);
    mxA = max3g(mxA, scA[1][3], scA[2][0]);
    mxA = max3g(mxA, scA[2][1], scA[2][2]);
    mxA = max3g(mxA, scA[2][3], scA[3][0]);
    mxA = max3g(mxA, scA[3][1], scA[3][2]);
    mxA = fmaxf(mxA, scA[3][3]);
    float mxB = max3g(scB[0][0], scB[0][1], scB[0][2]);
    mxB = max3g(mxB, scB[0][3], scB[1][0]);
    mxB = max3g(mxB, scB[1][1], scB[1][2]);
    mxB = max3g(mxB, scB[1][3], scB[2][0]);
    mxB = max3g(mxB, scB[2][1], scB[2][2]);
    mxB = max3g(mxB, scB[2][3], scB[3][0]);
    mxB = max3g(mxB, scB[3][1], scB[3][2]);
    mxB = fmaxf(mxB, scB[3][3]);
#pragma unroll
    for (int nk = 0; nk < 4; ++nk)
#pragma unroll
      for (int r = 0; r < 4; ++r) {
        scA[nk][r] = exp2g(scA[nk][r]);
        scB[nk][r] = exp2g(scB[nk][r]);
      }
    if (!__all(fmaxf(mxA, mxB) <= 8.0f)) {
      mxA = fmaxf(mxA, __shfl_xor(mxA, 16));
      mxA = fmaxf(mxA, __shfl_xor(mxA, 32));
      mxB = fmaxf(mxB, __shfl_xor(mxB, 16));
      mxB = fmaxf(mxB, __shfl_xor(mxB, 32));
      const float dA = fmaxf(mxA, 0.0f), dB = fmaxf(mxB, 0.0f);
      const float aA = exp2g(-dA), aB = exp2g(-dB);
      nmA -= dA; nmB -= dB;
#pragma unroll
      for (int nk = 0; nk < 4; ++nk)
#pragma unroll
        for (int r = 0; r < 4; ++r) { scA[nk][r] *= aA; scB[nk][r] *= aB; }
      accSA *= aA; accSB *= aB;
#pragma unroll
      for (int nd = 0; nd < 4; ++nd) { accA[nd] *= aA; accB[nd] *= aB; }
    }
    union PU { unsigned u[4]; bf16x8 v; } pA0, pA1, pB0, pB1;
    pA0.u[0] = cvtpk(scA[0][0], scA[0][1]); pA0.u[1] = cvtpk(scA[0][2], scA[0][3]);
    pA0.u[2] = cvtpk(scA[2][0], scA[2][1]); pA0.u[3] = cvtpk(scA[2][2], scA[2][3]);
    pA1.u[0] = cvtpk(scA[1][0], scA[1][1]); pA1.u[1] = cvtpk(scA[1][2], scA[1][3]);
    pA1.u[2] = cvtpk(scA[3][0], scA[3][1]); pA1.u[3] = cvtpk(scA[3][2], scA[3][3]);
    pB0.u[0] = cvtpk(scB[0][0], scB[0][1]); pB0.u[1] = cvtpk(scB[0][2], scB[0][3]);
    pB0.u[2] = cvtpk(scB[2][0], scB[2][1]); pB0.u[3] = cvtpk(scB[2][2], scB[2][3]);
    pB1.u[0] = cvtpk(scB[1][0], scB[1][1]); pB1.u[1] = cvtpk(scB[1][2], scB[1][3]);
    pB1.u[2] = cvtpk(scB[3][0], scB[3][1]); pB1.u[3] = cvtpk(scB[3][2], scB[3][3]);
    __builtin_amdgcn_s_setprio(1);
    accSA = __builtin_amdgcn_mfma_f32_16x16x32_bf16(pA0.v, onesf, accSA, 0, 0, 0);
    accSA = __builtin_amdgcn_mfma_f32_16x16x32_bf16(pA1.v, onesf, accSA, 0, 0, 0);
    accSB = __builtin_amdgcn_mfma_f32_16x16x32_bf16(pB0.v, onesf, accSB, 0, 0, 0);
    accSB = __builtin_amdgcn_mfma_f32_16x16x32_bf16(pB1.v, onesf, accSB, 0, 0, 0);
#pragma unroll
    for (int nd = 0; nd < 4; ++nd) {
      bf16x8 vf0 = *(const bf16x8*)&vt[(nd * 2 + 0) * 512 + lane * 8];
      accA[nd] = __builtin_amdgcn_mfma_f32_16x16x32_bf16(pA0.v, vf0, accA[nd], 0, 0, 0);
      accB[nd] = __builtin_amdgcn_mfma_f32_16x16x32_bf16(pB0.v, vf0, accB[nd], 0, 0, 0);
      bf16x8 vf1 = *(const bf16x8*)&vt[(nd * 2 + 1) * 512 + lane * 8];
      accA[nd] = __builtin_amdgcn_mfma_f32_16x16x32_bf16(pA1.v, vf1, accA[nd], 0, 0, 0);
      accB[nd] = __builtin_amdgcn_mfma_f32_16x16x32_bf16(pB1.v, vf1, accB[nd], 0, 0, 0);
    }
    __builtin_amdgcn_s_setprio(0);
    __syncthreads();
  }
#pragma unroll
  for (int r = 0; r < 4; ++r) {
    const float invA = rcpg(__shfl(accSA[r], hi << 4));
    const float invB = rcpg(__shfl(accSB[r], hi << 4));
    const int srA = q0 + hi * 4 + r;
    const size_t roA = ((size_t)bI * S_ + srA) * H_ + h * HD_;
    const size_t roB = ((size_t)bI * S_ + srA + 64) * H_ + h * HD_;
#pragma unroll
    for (int nd = 0; nd < 4; ++nd) {
      ctx[roA + nd * 16 + lo] = f2bf(accA[nd][r] * invA);
      ctx[roB + nd * 16 + lo] = f2bf(accB[nd][r] * invB);
    }
  }
}

// ---------------- launch -------------------------------------------------------
extern "C" void kernel_launch(void* const* d_in, const int* in_sizes, int n_in,
                              void* d_out, int out_size, void* d_ws, size_t ws_size,
                              hipStream_t stream) {
  const float* x    = (const float*)d_in[0];
  const float* ln1w = (const float*)d_in[1];
  const float* ln1b = (const float*)d_in[2];
  const float* wq   = (const float*)d_in[3];
  const float* bq   = (const float*)d_in[4];
  const float* wk   = (const float*)d_in[5];
  const float* bk   = (const float*)d_in[6];
  const float* wvp  = (const float*)d_in[7];
  const float* bv   = (const float*)d_in[8];
  const float* wo   = (const float*)d_in[9];
  const float* bo   = (const float*)d_in[10];
  const float* ln2w = (const float*)d_in[11];
  const float* ln2b = (const float*)d_in[12];
  const float* w1   = (const float*)d_in[13];
  const float* b1   = (const float*)d_in[14];
  const float* w2   = (const float*)d_in[15];
  const float* b2   = (const float*)d_in[16];
  float* out = (float*)d_out;

  short* ws = (short*)d_ws;
  short* wqkvT = ws;                              // [2304][768]
  short* woT   = wqkvT + (size_t)2304 * 768;      // [768][768]
  short* w1T   = woT + (size_t)768 * 768;         // [3072][768]
  short* w2T   = w1T + (size_t)3072 * 768;        // [768][3072]
  short* xn    = w2T + (size_t)768 * 3072;        // [8192][768] (reused as xn2)
  short* qb    = xn + (size_t)M_ * H_;            // [48][2048][64]
  short* kb    = qb + (size_t)M_ * H_;
  short* vb    = kb + (size_t)M_ * H_;            // V^T: [48][64][2048]
  short* ctx   = vb + (size_t)M_ * H_;            // [8192][768]
  short* yb    = qb;                              // reuse q..ctx: [8192][3072]
  float* x1    = (float*)(ctx + (size_t)M_ * H_); // [8192][768] fp32

  tcast_all<<<6912, dim3(32, 8), 0, stream>>>(wq, wk, wvp, wo, w1, w2,
      wqkvT, wqkvT + (size_t)768 * 768, wqkvT + (size_t)2 * 768 * 768, woT,
      w1T, w2T);

  ln_fwd<<<M_, 256, 0, stream>>>(x, ln1w, ln1b, xn);

  gemm_bt8<0><<<dim3(18, 64), 512, 0, stream>>>(xn, wqkvT, 768, 2304,
      bq, bk, bv, nullptr, qb, kb, vb);

  attn_fwd<<<dim3(16, 48), 256, 0, stream>>>(qb, kb, vb, ctx);

  gemm_bt<1><<<dim3(12, 64), 256, 0, stream>>>(ctx, woT, 768, 768,
      bo, x, x1, nullptr);

  ln_fwd<<<M_, 256, 0, stream>>>(x1, ln2w, ln2b, xn);

  gemm_bt8<2><<<dim3(24, 64), 512, 0, stream>>>(xn, w1T, 768, 3072,
      b1, nullptr, nullptr, yb, nullptr, nullptr, nullptr);

  gemm_bt<1><<<dim3(12, 64), 256, 0, stream>>>(yb, w2T, 3072, 768,
      b2, x1, out, nullptr);
}

// Round 17
// 276.720 us; speedup vs baseline: 1.2698x; 1.0039x over previous
//
#include <hip/hip_runtime.h>
#include <hip/hip_bf16.h>

#define B_ 4
#define S_ 2048
#define H_ 768
#define NH_ 12
#define HD_ 64
#define MLP_ 3072
#define M_ (B_*S_)

typedef float f32x4 __attribute__((ext_vector_type(4)));
typedef short bf16x8 __attribute__((ext_vector_type(8)));

__device__ __forceinline__ short f2bf(float f) {
  union { float f; unsigned u; } x; x.f = f;
  unsigned r = (x.u + 0x7fffu + ((x.u >> 16) & 1u)) >> 16;
  return (short)(unsigned short)r;
}

__device__ __forceinline__ float exp2g(float x) {   // raw v_exp_f32 (2^x)
  float r; asm("v_exp_f32 %0, %1" : "=v"(r) : "v"(x)); return r;
}
__device__ __forceinline__ float rcpg(float x) {    // raw v_rcp_f32
  float r; asm("v_rcp_f32 %0, %1" : "=v"(r) : "v"(x)); return r;
}
__device__ __forceinline__ float max3g(float a, float b, float c) {
  float r; asm("v_max3_f32 %0, %1, %2, %3" : "=v"(r) : "v"(a), "v"(b), "v"(c)); return r;
}
__device__ __forceinline__ unsigned cvtpk(float a, float b) { // [bf16(a)|bf16(b)<<16]
  unsigned r; asm("v_cvt_pk_bf16_f32 %0, %1, %2" : "=v"(r) : "v"(a), "v"(b)); return r;
}

typedef __attribute__((address_space(1))) const void gvoid;
typedef __attribute__((address_space(3))) void lvoid;
__device__ __forceinline__ void async16(const void* g, void* l) {
  __builtin_amdgcn_global_load_lds((gvoid*)g, (lvoid*)l, 16, 0, 0);
}

// bijective XCD chunk swizzle (m204)
__device__ __forceinline__ int xcd_swz(int h, int nwg) {
  const int q = nwg >> 3, r = nwg & 7;
  const int xc = h & 7, i = h >> 3;
  return (xc < r ? xc * (q + 1) : r * (q + 1) + (xc - r) * q) + i;
}

// ---------------- fused prep: 6 weight transposes + LN1, ONE launch ------------
// blocks [0,8192): LN1 row = bid (x fp32 -> xn bf16)
// blocks [8192,15104): transposes (same decode as r16 tcast_all, bid-8192)
__global__ __launch_bounds__(256)
void prep_all(const float* __restrict__ x, const float* __restrict__ ln1w,
              const float* __restrict__ ln1b, short* __restrict__ xn,
              const float* __restrict__ wq, const float* __restrict__ wk,
              const float* __restrict__ wv, const float* __restrict__ wo,
              const float* __restrict__ w1, const float* __restrict__ w2,
              short* __restrict__ oq, short* __restrict__ ok,
              short* __restrict__ ov, short* __restrict__ oo,
              short* __restrict__ o1, short* __restrict__ o2) {
  __shared__ float tile[32][33];
  __shared__ float red[4];
  const int t = threadIdx.y * 32 + threadIdx.x;   // flat 0..255
  const int bid = blockIdx.x;
  if (bid < 8192) {
    // ---- LN1 row ----
    const int row = bid;
    const float* xr = x + (size_t)row * H_;
    const float v0 = xr[t], v1 = xr[t + 256], v2 = xr[t + 512];
    float s = v0 + v1 + v2;
#pragma unroll
    for (int o = 32; o > 0; o >>= 1) s += __shfl_down(s, o);
    if ((t & 63) == 0) red[t >> 6] = s;
    __syncthreads();
    const float mean = (red[0] + red[1] + red[2] + red[3]) * (1.0f / H_);
    __syncthreads();
    const float d0 = v0 - mean, d1 = v1 - mean, d2 = v2 - mean;
    float vv = d0 * d0 + d1 * d1 + d2 * d2;
#pragma unroll
    for (int o = 32; o > 0; o >>= 1) vv += __shfl_down(vv, o);
    if ((t & 63) == 0) red[t >> 6] = vv;
    __syncthreads();
    const float var = (red[0] + red[1] + red[2] + red[3]) * (1.0f / H_);
    const float rstd = rsqrtf(var + 1e-6f);
    short* orow = xn + (size_t)row * H_;
    orow[t]       = f2bf(d0 * rstd * ln1w[t] + ln1b[t]);
    orow[t + 256] = f2bf(d1 * rstd * ln1w[t + 256] + ln1b[t + 256]);
    orow[t + 512] = f2bf(d2 * rstd * ln1w[t + 512] + ln1b[t + 512]);
    return;
  }
  // ---- weight transpose+cast: out[n*K+k] = bf16(in[k*N+n]) ----
  const int tb = bid - 8192;
  const float* in; short* out; int K, N, bx, by;
  if (tb < 2304) {
    const int z = tb / 576, r = tb - z * 576;
    bx = r % 24; by = r / 24; K = 768; N = 768;
    in  = (z == 0) ? wq : (z == 1) ? wk : (z == 2) ? wv : wo;
    out = (z == 0) ? oq : (z == 1) ? ok : (z == 2) ? ov : oo;
  } else if (tb < 4608) {
    const int r = tb - 2304; bx = r % 96; by = r / 96; K = 768; N = 3072;
    in = w1; out = o1;
  } else {
    const int r = tb - 4608; bx = r % 24; by = r / 24; K = 3072; N = 768;
    in = w2; out = o2;
  }
  const int n0 = bx * 32, k0 = by * 32;
  const int tx = threadIdx.x, ty = threadIdx.y;
#pragma unroll
  for (int i = 0; i < 4; ++i)
    tile[ty * 4 + i][tx] = in[(size_t)(k0 + ty * 4 + i) * N + n0 + tx];
  __syncthreads();
#pragma unroll
  for (int i = 0; i < 4; ++i)
    out[(size_t)(n0 + ty * 4 + i) * K + k0 + tx] = f2bf(tile[tx][ty * 4 + i]);
}

// ---------------- layernorm (row of 768) -> bf16 (LN2) -------------------------
__device__ __forceinline__ float block_sum256(float v) {
  __shared__ float red[4];
#pragma unroll
  for (int o = 32; o > 0; o >>= 1) v += __shfl_down(v, o);
  if ((threadIdx.x & 63) == 0) red[threadIdx.x >> 6] = v;
  __syncthreads();
  v = red[0] + red[1] + red[2] + red[3];
  __syncthreads();
  return v;
}

__global__ __launch_bounds__(256)
void ln_fwd(const float* __restrict__ xin, const float* __restrict__ g,
            const float* __restrict__ bt, short* __restrict__ o) {
  const int row = blockIdx.x, t = threadIdx.x;
  const float* xr = xin + (size_t)row * H_;
  const float v0 = xr[t], v1 = xr[t + 256], v2 = xr[t + 512];
  const float mean = block_sum256(v0 + v1 + v2) * (1.0f / H_);
  const float d0 = v0 - mean, d1 = v1 - mean, d2 = v2 - mean;
  const float var = block_sum256(d0 * d0 + d1 * d1 + d2 * d2) * (1.0f / H_);
  const float rstd = rsqrtf(var + 1e-6f);
  short* orow = o + (size_t)row * H_;
  orow[t]       = f2bf(d0 * rstd * g[t] + bt[t]);
  orow[t + 256] = f2bf(d1 * rstd * g[t + 256] + bt[t + 256]);
  orow[t + 512] = f2bf(d2 * rstd * g[t + 512] + bt[t + 512]);
}

#define QSCALE 0.18033688011112042f   /* 0.125 * log2(e) */

// ---------------- 4-wave GEMM (TN=64) — r12-exact, for proj/MLP2 (N=768) ------
template<int MODE>
__global__ __launch_bounds__(256)
void gemm_bt(const short* __restrict__ A, const short* __restrict__ Bw,
             int K, int N,
             const float* __restrict__ b0,
             const float* __restrict__ resid,
             float* __restrict__ outf, short* __restrict__ outh) {
  __shared__ short As[2][128 * 64];
  __shared__ short Bs[2][64 * 64];
  const int tid = threadIdx.x;
  const int wv = tid >> 6, lane = tid & 63;
  const int lo = lane & 15, hi = lane >> 4;
  const int wr = wv >> 1, wc = wv & 1;

  const int GX = gridDim.x;
  const int logical = xcd_swz(blockIdx.y * GX + blockIdx.x, GX * gridDim.y);
  const int bn = logical % GX, bm = logical / GX;

  const short* Ab = A + (size_t)bm * 128 * K;
  const short* Bb = Bw + (size_t)bn * 64 * K;
  const int srow = lane >> 3;
  const int scol = ((lane & 7) ^ srow) * 8;

  auto stage = [&](int buf, int kt) {
#pragma unroll
    for (int c = 0; c < 4; ++c) {
      const int rb = wv * 32 + c * 8;
      async16(Ab + (size_t)(rb + srow) * K + kt + scol, &As[buf][rb * 64]);
    }
#pragma unroll
    for (int c = 0; c < 2; ++c) {
      const int rb = wv * 16 + c * 8;
      async16(Bb + (size_t)(rb + srow) * K + kt + scol, &Bs[buf][rb * 64]);
    }
  };

  f32x4 acc[4][2] = {};
  stage(0, 0);
  const int nIt = K >> 6;
  for (int it = 0; it < nIt; ++it) {
    __syncthreads();
    if (it + 1 < nIt) stage((it + 1) & 1, (it + 1) << 6);
    const short* as = As[it & 1];
    const short* bs = Bs[it & 1];
#pragma unroll
    for (int ks = 0; ks < 2; ++ks) {
      const int rc = (((ks * 4 + hi) ^ (lo & 7)) * 8);
      bf16x8 af[4], bfr[2];
#pragma unroll
      for (int m = 0; m < 4; ++m)
        af[m] = *(const bf16x8*)&as[(wr * 64 + m * 16 + lo) * 64 + rc];
#pragma unroll
      for (int n = 0; n < 2; ++n)
        bfr[n] = *(const bf16x8*)&bs[(wc * 32 + n * 16 + lo) * 64 + rc];
#pragma unroll
      for (int m = 0; m < 4; ++m)
#pragma unroll
        for (int n = 0; n < 2; ++n)
          acc[m][n] = __builtin_amdgcn_mfma_f32_16x16x32_bf16(af[m], bfr[n], acc[m][n], 0, 0, 0);
    }
  }
  const int colBase = bn * 64 + wc * 32;
  const int rowBase = bm * 128 + wr * 64;
#pragma unroll
  for (int m = 0; m < 4; ++m) {
#pragma unroll
    for (int n = 0; n < 2; ++n) {
#pragma unroll
      for (int r = 0; r < 4; ++r) {
        const int row = rowBase + m * 16 + hi * 4 + r;
        const int col = colBase + n * 16 + lo;
        float val = acc[m][n][r] + b0[col];
        if (MODE == 1) {
          val += resid[(size_t)row * N + col];
          outf[(size_t)row * N + col] = val;
        } else {
          const float u = val * (0.7978845608f + 0.0356774081f * val * val);
          const float e = exp2g(-2.885390082f * u);
          val = val * rcpg(1.0f + e);
          outh[(size_t)row * N + col] = f2bf(val);
        }
      }
    }
  }
}

// ---------------- 8-wave GEMM (TN=128) — 2-phase schedule; QKV/MLP1 -----------
template<int MODE>
__global__ __launch_bounds__(512)
void gemm_bt8(const short* __restrict__ A, const short* __restrict__ Bw,
              int K, int N,
              const float* __restrict__ b0, const float* __restrict__ b1,
              const float* __restrict__ b2,
              short* __restrict__ outh,
              short* __restrict__ oq, short* __restrict__ ok2, short* __restrict__ ov) {
  __shared__ short As[2][128 * 64];
  __shared__ short Bs[2][128 * 64];
  const int tid = threadIdx.x;
  const int wv = tid >> 6, lane = tid & 63;
  const int lo = lane & 15, hi = lane >> 4;
  const int wr = wv >> 2, wc = wv & 3;

  const int GX = gridDim.x;
  const int logical = xcd_swz(blockIdx.y * GX + blockIdx.x, GX * gridDim.y);
  const int bn = logical % GX, bm = logical / GX;

  const short* Ab = A + (size_t)bm * 128 * K;
  const short* Bb = Bw + (size_t)bn * 128 * K;
  const int srow = lane >> 3;
  const int scol = ((lane & 7) ^ srow) * 8;

  auto stage = [&](int buf, int kt) {
#pragma unroll
    for (int c = 0; c < 2; ++c) {
      const int rb = wv * 16 + c * 8;
      async16(Ab + (size_t)(rb + srow) * K + kt + scol, &As[buf][rb * 64]);
    }
#pragma unroll
    for (int c = 0; c < 2; ++c) {
      const int rb = wv * 16 + c * 8;
      async16(Bb + (size_t)(rb + srow) * K + kt + scol, &Bs[buf][rb * 64]);
    }
  };

  f32x4 acc[4][2] = {};
  stage(0, 0);
  const int nIt = K >> 6;
  for (int it = 0; it < nIt; ++it) {
    __syncthreads();
    if (it + 1 < nIt) stage((it + 1) & 1, (it + 1) << 6);
    const short* as = As[it & 1];
    const short* bs = Bs[it & 1];
#pragma unroll
    for (int ks = 0; ks < 2; ++ks) {
      const int rc = (((ks * 4 + hi) ^ (lo & 7)) * 8);
      bf16x8 af[4], bfr[2];
#pragma unroll
      for (int m = 0; m < 4; ++m)
        af[m] = *(const bf16x8*)&as[(wr * 64 + m * 16 + lo) * 64 + rc];
#pragma unroll
      for (int n = 0; n < 2; ++n)
        bfr[n] = *(const bf16x8*)&bs[(wc * 32 + n * 16 + lo) * 64 + rc];
#pragma unroll
      for (int m = 0; m < 4; ++m)
#pragma unroll
        for (int n = 0; n < 2; ++n)
          acc[m][n] = __builtin_amdgcn_mfma_f32_16x16x32_bf16(af[m], bfr[n], acc[m][n], 0, 0, 0);
    }
  }
  const int colBase = bn * 128 + wc * 32;
  const int rowBase = bm * 128 + wr * 64;
#pragma unroll
  for (int m = 0; m < 4; ++m) {
#pragma unroll
    for (int n = 0; n < 2; ++n) {
#pragma unroll
      for (int r = 0; r < 4; ++r) {
        const int row = rowBase + m * 16 + hi * 4 + r;
        const int col = colBase + n * 16 + lo;
        float val = acc[m][n][r];
        if (MODE == 0) {
          const int which = col / H_;
          const int nn = col - which * H_;
          val += (which == 0 ? b0 : which == 1 ? b1 : b2)[nn];
          if (which == 0) val *= QSCALE;
          const int h = nn >> 6, d = nn & 63;
          const int bI = row >> 11, s = row & (S_ - 1);
          const short bv16 = f2bf(val);
          if (which == 2) {
            const int sl = s & 63;
            const int pc = ((sl >> 4) & 1) * 32 + ((sl >> 2) & 3) * 8
                         + ((sl >> 5) & 1) * 4 + (sl & 3);
            ov[(((size_t)bI * NH_ + h) * HD_ + d) * S_ + (s & ~63) + pc] = bv16;
          } else {
            short* dst = (which == 0 ? oq : ok2);
            dst[(((size_t)bI * NH_ + h) * S_ + s) * HD_ + d] = bv16;
          }
        } else {
          val += b0[col];
          const float u = val * (0.7978845608f + 0.0356774081f * val * val);
          const float e = exp2g(-2.885390082f * u);
          val = val * rcpg(1.0f + e);
          outh[(size_t)row * N + col] = f2bf(val);
        }
      }
    }
  }
}

// ---------------- flash attention (swapped QK^T, P in registers, 2 q-groups) ---
__global__ __launch_bounds__(256)
void attn_fwd(const short* __restrict__ qbuf, const short* __restrict__ kbuf,
              const short* __restrict__ vbuf, short* __restrict__ ctx) {
  __shared__ short Ks[2][8 * 512];
  __shared__ short Vt[2][8 * 512];
  const int tid = threadIdx.x;
  const int wv = tid >> 6, lane = tid & 63;
  const int lo = lane & 15, hi = lane >> 4;
  const int logical = xcd_swz(blockIdx.y * 16 + blockIdx.x, 16 * 48);
  const int qt = logical & 15, bh = logical >> 4;
  const int bI = bh / NH_, h = bh - bI * NH_;
  const size_t baseBH = (size_t)bh * S_ * HD_;
  const int q0 = qt * 128 + wv * 16;

  bf16x8 qfA[2], qfB[2];
#pragma unroll
  for (int k2 = 0; k2 < 2; ++k2) {
    qfA[k2] = *(const bf16x8*)&qbuf[baseBH + (size_t)(q0 + lo) * HD_ + k2 * 32 + hi * 8];
    qfB[k2] = *(const bf16x8*)&qbuf[baseBH + (size_t)(q0 + 64 + lo) * HD_ + k2 * 32 + hi * 8];
  }

  f32x4 accA[4] = {}, accB[4] = {};
  f32x4 accSA = {}, accSB = {};
  float nmA = 0.0f, nmB = 0.0f;

  const short oo = (lo == 0) ? (short)0x3F80 : (short)0;
  const bf16x8 onesf = {oo, oo, oo, oo, oo, oo, oo, oo};

  const short* ksrc = kbuf + baseBH + (size_t)(wv * 16 + lo) * HD_ + hi * 8;
  const short* vsrc = vbuf + baseBH + (size_t)(wv * 16 + lo) * S_ + hi * 8;
  const int dst0 = wv * 1024 + lane * 8;

  bf16x8 kreg0, kreg1, vreg0, vreg1;
  kreg0 = *(const bf16x8*)(ksrc);
  kreg1 = *(const bf16x8*)(ksrc + 32);
  vreg0 = *(const bf16x8*)(vsrc);
  vreg1 = *(const bf16x8*)(vsrc + 32);
  *(bf16x8*)&Ks[0][dst0] = kreg0;
  *(bf16x8*)&Ks[0][dst0 + 512] = kreg1;
  *(bf16x8*)&Vt[0][dst0] = vreg0;
  *(bf16x8*)&Vt[0][dst0 + 512] = vreg1;
  kreg0 = *(const bf16x8*)(ksrc + (size_t)64 * HD_);
  kreg1 = *(const bf16x8*)(ksrc + (size_t)64 * HD_ + 32);
  vreg0 = *(const bf16x8*)(vsrc + 64);
  vreg1 = *(const bf16x8*)(vsrc + 64 + 32);
  __syncthreads();

  for (int t = 0; t < S_ / 64; ++t) {
    const int cur = t & 1, nxt = cur ^ 1;
    *(bf16x8*)&Ks[nxt][dst0] = kreg0;
    *(bf16x8*)&Ks[nxt][dst0 + 512] = kreg1;
    *(bf16x8*)&Vt[nxt][dst0] = vreg0;
    *(bf16x8*)&Vt[nxt][dst0 + 512] = vreg1;
    {
      const int tn = (t + 2 < S_ / 64) ? t + 2 : S_ / 64 - 1;
      const short* kp = ksrc + (size_t)tn * 64 * HD_;
      kreg0 = *(const bf16x8*)(kp);
      kreg1 = *(const bf16x8*)(kp + 32);
      const short* vp = vsrc + tn * 64;
      vreg0 = *(const bf16x8*)(vp);
      vreg1 = *(const bf16x8*)(vp + 32);
    }
    const short* ks = Ks[cur];
    const short* vt = Vt[cur];
    const f32x4 ciA = {nmA, nmA, nmA, nmA};
    const f32x4 ciB = {nmB, nmB, nmB, nmB};
    f32x4 scA[4], scB[4];
    __builtin_amdgcn_s_setprio(1);
#pragma unroll
    for (int nk = 0; nk < 4; ++nk) {
      f32x4 zA = ciA, zB = ciB;
#pragma unroll
      for (int k2 = 0; k2 < 2; ++k2) {
        bf16x8 kf = *(const bf16x8*)&ks[(nk * 2 + k2) * 512 + lane * 8];
        zA = __builtin_amdgcn_mfma_f32_16x16x32_bf16(kf, qfA[k2], zA, 0, 0, 0);
        zB = __builtin_amdgcn_mfma_f32_16x16x32_bf16(kf, qfB[k2], zB, 0, 0, 0);
      }
      scA[nk] = zA; scB[nk] = zB;
    }
    __builtin_amdgcn_s_setprio(0);
    float mxA = max3g(scA[0][0], scA[0][1], scA[0][2]);
    mxA = max3g(mxA, scA[0][3], scA[1][0]);
    mxA = max3g(mxA, scA[1][1], scA[1][2]);
    mxA = max3g(mxA, scA[1][3], scA[2][0]);
    mxA = max3g(mxA, scA[2][1], scA[2][2]);
    mxA = max3g(mxA, scA[2][3], scA[3][0]);
    mxA = max3g(mxA, scA[3][1], scA[3][2]);
    mxA = fmaxf(mxA, scA[3][3]);
    float mxB = max3g(scB[0][0], scB[0][1], scB[0][2]);
    mxB = max3g(mxB, scB[0][3], scB[1][0]);
    mxB = max3g(mxB, scB[1][1], scB[1][2]);
    mxB = max3g(mxB, scB[1][3], scB[2][0]);
    mxB = max3g(mxB, scB[2][1], scB[2][2]);
    mxB = max3g(mxB, scB[2][3], scB[3][0]);
    mxB = max3g(mxB, scB[3][1], scB[3][2]);
    mxB = fmaxf(mxB, scB[3][3]);
#pragma unroll
    for (int nk = 0; nk < 4; ++nk)
#pragma unroll
      for (int r = 0; r < 4; ++r) {
        scA[nk][r] = exp2g(scA[nk][r]);
        scB[nk][r] = exp2g(scB[nk][r]);
      }
    if (!__all(fmaxf(mxA, mxB) <= 8.0f)) {
      mxA = fmaxf(mxA, __shfl_xor(mxA, 16));
      mxA = fmaxf(mxA, __shfl_xor(mxA, 32));
      mxB = fmaxf(mxB, __shfl_xor(mxB, 16));
      mxB = fmaxf(mxB, __shfl_xor(mxB, 32));
      const float dA = fmaxf(mxA, 0.0f), dB = fmaxf(mxB, 0.0f);
      const float aA = exp2g(-dA), aB = exp2g(-dB);
      nmA -= dA; nmB -= dB;
#pragma unroll
      for (int nk = 0; nk < 4; ++nk)
#pragma unroll
        for (int r = 0; r < 4; ++r) { scA[nk][r] *= aA; scB[nk][r] *= aB; }
      accSA *= aA; accSB *= aB;
#pragma unroll
      for (int nd = 0; nd < 4; ++nd) { accA[nd] *= aA; accB[nd] *= aB; }
    }
    union PU { unsigned u[4]; bf16x8 v; } pA0, pA1, pB0, pB1;
    pA0.u[0] = cvtpk(scA[0][0], scA[0][1]); pA0.u[1] = cvtpk(scA[0][2], scA[0][3]);
    pA0.u[2] = cvtpk(scA[2][0], scA[2][1]); pA0.u[3] = cvtpk(scA[2][2], scA[2][3]);
    pA1.u[0] = cvtpk(scA[1][0], scA[1][1]); pA1.u[1] = cvtpk(scA[1][2], scA[1][3]);
    pA1.u[2] = cvtpk(scA[3][0], scA[3][1]); pA1.u[3] = cvtpk(scA[3][2], scA[3][3]);
    pB0.u[0] = cvtpk(scB[0][0], scB[0][1]); pB0.u[1] = cvtpk(scB[0][2], scB[0][3]);
    pB0.u[2] = cvtpk(scB[2][0], scB[2][1]); pB0.u[3] = cvtpk(scB[2][2], scB[2][3]);
    pB1.u[0] = cvtpk(scB[1][0], scB[1][1]); pB1.u[1] = cvtpk(scB[1][2], scB[1][3]);
    pB1.u[2] = cvtpk(scB[3][0], scB[3][1]); pB1.u[3] = cvtpk(scB[3][2], scB[3][3]);
    __builtin_amdgcn_s_setprio(1);
    accSA = __builtin_amdgcn_mfma_f32_16x16x32_bf16(pA0.v, onesf, accSA, 0, 0, 0);
    accSA = __builtin_amdgcn_mfma_f32_16x16x32_bf16(pA1.v, onesf, accSA, 0, 0, 0);
    accSB = __builtin_amdgcn_mfma_f32_16x16x32_bf16(pB0.v, onesf, accSB, 0, 0, 0);
    accSB = __builtin_amdgcn_mfma_f32_16x16x32_bf16(pB1.v, onesf, accSB, 0, 0, 0);
#pragma unroll
    for (int nd = 0; nd < 4; ++nd) {
      bf16x8 vf0 = *(const bf16x8*)&vt[(nd * 2 + 0) * 512 + lane * 8];
      accA[nd] = __builtin_amdgcn_mfma_f32_16x16x32_bf16(pA0.v, vf0, accA[nd], 0, 0, 0);
      accB[nd] = __builtin_amdgcn_mfma_f32_16x16x32_bf16(pB0.v, vf0, accB[nd], 0, 0, 0);
      bf16x8 vf1 = *(const bf16x8*)&vt[(nd * 2 + 1) * 512 + lane * 8];
      accA[nd] = __builtin_amdgcn_mfma_f32_16x16x32_bf16(pA1.v, vf1, accA[nd], 0, 0, 0);
      accB[nd] = __builtin_amdgcn_mfma_f32_16x16x32_bf16(pB1.v, vf1, accB[nd], 0, 0, 0);
    }
    __builtin_amdgcn_s_setprio(0);
    __syncthreads();
  }
#pragma unroll
  for (int r = 0; r < 4; ++r) {
    const float invA = rcpg(__shfl(accSA[r], hi << 4));
    const float invB = rcpg(__shfl(accSB[r], hi << 4));
    const int srA = q0 + hi * 4 + r;
    const size_t roA = ((size_t)bI * S_ + srA) * H_ + h * HD_;
    const size_t roB = ((size_t)bI * S_ + srA + 64) * H_ + h * HD_;
#pragma unroll
    for (int nd = 0; nd < 4; ++nd) {
      ctx[roA + nd * 16 + lo] = f2bf(accA[nd][r] * invA);
      ctx[roB + nd * 16 + lo] = f2bf(accB[nd][r] * invB);
    }
  }
}

// ---------------- launch -------------------------------------------------------
extern "C" void kernel_launch(void* const* d_in, const int* in_sizes, int n_in,
                              void* d_out, int out_size, void* d_ws, size_t ws_size,
                              hipStream_t stream) {
  const float* x    = (const float*)d_in[0];
  const float* ln1w = (const float*)d_in[1];
  const float* ln1b = (const float*)d_in[2];
  const float* wq   = (const float*)d_in[3];
  const float* bq   = (const float*)d_in[4];
  const float* wk   = (const float*)d_in[5];
  const float* bk   = (const float*)d_in[6];
  const float* wvp  = (const float*)d_in[7];
  const float* bv   = (const float*)d_in[8];
  const float* wo   = (const float*)d_in[9];
  const float* bo   = (const float*)d_in[10];
  const float* ln2w = (const float*)d_in[11];
  const float* ln2b = (const float*)d_in[12];
  const float* w1   = (const float*)d_in[13];
  const float* b1   = (const float*)d_in[14];
  const float* w2   = (const float*)d_in[15];
  const float* b2   = (const float*)d_in[16];
  float* out = (float*)d_out;

  short* ws = (short*)d_ws;
  short* wqkvT = ws;                              // [2304][768]
  short* woT   = wqkvT + (size_t)2304 * 768;      // [768][768]
  short* w1T   = woT + (size_t)768 * 768;         // [3072][768]
  short* w2T   = w1T + (size_t)3072 * 768;        // [768][3072]
  short* xn    = w2T + (size_t)768 * 3072;        // [8192][768] (reused as xn2)
  short* qb    = xn + (size_t)M_ * H_;            // [48][2048][64]
  short* kb    = qb + (size_t)M_ * H_;
  short* vb    = kb + (size_t)M_ * H_;            // V^T: [48][64][2048]
  short* ctx   = vb + (size_t)M_ * H_;            // [8192][768]
  short* yb    = qb;                              // reuse q..ctx: [8192][3072]
  float* x1    = (float*)(ctx + (size_t)M_ * H_); // [8192][768] fp32

  prep_all<<<15104, dim3(32, 8), 0, stream>>>(x, ln1w, ln1b, xn,
      wq, wk, wvp, wo, w1, w2,
      wqkvT, wqkvT + (size_t)768 * 768, wqkvT + (size_t)2 * 768 * 768, woT,
      w1T, w2T);

  gemm_bt8<0><<<dim3(18, 64), 512, 0, stream>>>(xn, wqkvT, 768, 2304,
      bq, bk, bv, nullptr, qb, kb, vb);

  attn_fwd<<<dim3(16, 48), 256, 0, stream>>>(qb, kb, vb, ctx);

  gemm_bt<1><<<dim3(12, 64), 256, 0, stream>>>(ctx, woT, 768, 768,
      bo, x, x1, nullptr);

  ln_fwd<<<M_, 256, 0, stream>>>(x1, ln2w, ln2b, xn);

  gemm_bt8<2><<<dim3(24, 64), 512, 0, stream>>>(xn, w1T, 768, 3072,
      b1, nullptr, nullptr, yb, nullptr, nullptr, nullptr);

  gemm_bt<1><<<dim3(12, 64), 256, 0, stream>>>(yb, w2T, 3072, 768,
      b2, x1, out, nullptr);
}